// Round 3
// baseline (614.197 us; speedup 1.0000x reference)
//
#include <hip/hip_runtime.h>
#include <math.h>

// LorentzMLA — bf16 MFMA implementation, key-split flash attention.
// S=2048, DIM=2048, H=16, NOPE=128, ROPE_SP=64, QK_HD=193 (pad 224),
// KV_RANK=512 (kv_pt 513 pad 544), VHD=128. Causal mask hard-coded.

typedef unsigned short u16;
typedef unsigned int u32;
typedef __attribute__((ext_vector_type(8))) short bf16x8;
typedef __attribute__((ext_vector_type(4))) float f32x4;

#define S_LEN 2048
#define NH 16
#define DPAD 224
#define CHUNK 512

__device__ __forceinline__ u16 f2bf(float f){
  u32 u = __builtin_bit_cast(u32, f);
  u32 r = u + 0x7fffu + ((u >> 16) & 1u);
  return (u16)(r >> 16);
}
__device__ __forceinline__ float bf2f(u16 h){
  u32 u = ((u32)h) << 16;
  return __builtin_bit_cast(float, u);
}

// ---------------- f32 -> bf16 cast, 8 elems/thread ----------------------------
__global__ __launch_bounds__(256) void cast_bf16x8(
    const float* __restrict__ in, u16* __restrict__ out)
{
  size_t i = ((size_t)blockIdx.x*256 + threadIdx.x)*8;
  float4 a = *(const float4*)(in + i);
  float4 b = *(const float4*)(in + i + 4);
  uint4 v;
  v.x = (u32)f2bf(a.x) | ((u32)f2bf(a.y) << 16);
  v.y = (u32)f2bf(a.z) | ((u32)f2bf(a.w) << 16);
  v.z = (u32)f2bf(b.x) | ((u32)f2bf(b.y) << 16);
  v.w = (u32)f2bf(b.z) | ((u32)f2bf(b.w) << 16);
  *(uint4*)(out + i) = v;
}

// ---------------- transpose + cast + zero-pad: out[n][k] = in[k][n] -----------
__global__ void transpose_cast(const float* __restrict__ in, u16* __restrict__ out,
                               int R, int Cc, int outR, int outC)
{
  __shared__ float t[32][33];
  const int tx = threadIdx.x, ty = threadIdx.y;
  const int bx = blockIdx.x*32, by = blockIdx.y*32;
  #pragma unroll
  for (int i=0;i<4;++i){
    int r = bx + ty + i*8, c = by + tx;
    t[ty+i*8][tx] = (r<R && c<Cc) ? in[(size_t)r*Cc + c] : 0.f;
  }
  __syncthreads();
  #pragma unroll
  for (int i=0;i<4;++i){
    int orow = by + ty + i*8, ocol = bx + tx;
    if (orow<outR && ocol<outC) out[(size_t)orow*outC + ocol] = f2bf(t[tx][ty+i*8]);
  }
}

// ---------------- bf16 MFMA GEMM: C[M][N] = A[M][K] @ BT[N][K]^T ---------------
__global__ __launch_bounds__(256) void gemm_bf16(
    const u16* __restrict__ A, const u16* __restrict__ BT, u16* __restrict__ C,
    int M, int N, int K)
{
  __shared__ __align__(16) u16 As[128*32];
  __shared__ __align__(16) u16 Bs[128*32];
  const int tid = threadIdx.x;
  const int bm = blockIdx.y*128, bn = blockIdx.x*128;
  const int w = tid>>6, lane = tid&63, lg = lane>>4, li = lane&15;
  const int wr = w>>1, wc = w&1;
  const int srow = tid>>2, q = tid&3;
  const int swz = (q ^ (srow&3)) << 3;

  const u16* Ap  = A  + (size_t)(bm+srow)*K + q*8;
  const u16* Ap2 = Ap + (size_t)64*K;
  const u16* Bp  = BT + (size_t)(bn+srow)*K + q*8;
  const u16* Bp2 = Bp + (size_t)64*K;
  u16* aw  = &As[srow*32 + swz];
  u16* aw2 = &As[(srow+64)*32 + swz];
  u16* bw  = &Bs[srow*32 + swz];
  u16* bw2 = &Bs[(srow+64)*32 + swz];
  const int rsw = (lg ^ (li&3)) << 3;
  const u16* ar = &As[(wr*64+li)*32 + rsw];
  const u16* br = &Bs[(wc*64+li)*32 + rsw];

  f32x4 acc[4][4];
  #pragma unroll
  for (int m=0;m<4;++m)
    #pragma unroll
    for (int n=0;n<4;++n) acc[m][n] = (f32x4){0.f,0.f,0.f,0.f};

  const int nk = K >> 5;
  bf16x8 ra  = *(const bf16x8*)Ap;
  bf16x8 ra2 = *(const bf16x8*)Ap2;
  bf16x8 rb  = *(const bf16x8*)Bp;
  bf16x8 rb2 = *(const bf16x8*)Bp2;
  for (int kt=0; kt<nk; ++kt){
    __syncthreads();
    *(bf16x8*)aw = ra;  *(bf16x8*)aw2 = ra2;
    *(bf16x8*)bw = rb;  *(bf16x8*)bw2 = rb2;
    __syncthreads();
    if (kt+1 < nk){
      const int ko = (kt+1)*32;
      ra  = *(const bf16x8*)(Ap+ko);  ra2 = *(const bf16x8*)(Ap2+ko);
      rb  = *(const bf16x8*)(Bp+ko);  rb2 = *(const bf16x8*)(Bp2+ko);
    }
    bf16x8 af[4], bg[4];
    #pragma unroll
    for (int m=0;m<4;++m) af[m] = *(const bf16x8*)(ar + m*16*32);
    #pragma unroll
    for (int n=0;n<4;++n) bg[n] = *(const bf16x8*)(br + n*16*32);
    #pragma unroll
    for (int m=0;m<4;++m)
      #pragma unroll
      for (int n=0;n<4;++n)
        acc[m][n] = __builtin_amdgcn_mfma_f32_16x16x32_bf16(af[m], bg[n], acc[m][n], 0,0,0);
  }
  #pragma unroll
  for (int m=0;m<4;++m){
    const int row = bm + wr*64 + m*16 + lg*4;
    #pragma unroll
    for (int n=0;n<4;++n){
      const int col = bn + wc*64 + n*16 + li;
      #pragma unroll
      for (int r=0;r<4;++r)
        C[(size_t)(row+r)*N + col] = f2bf(acc[m][n][r]);
    }
  }
}

// ---------------- kv_full(bf16) -> rmsnorm+project kv_pt(bf16 pad), rotary k_pe
__global__ __launch_bounds__(256) void build_kvpt(
    const u16* __restrict__ kvfull,  // [S][640], cols 0..575 valid
    const float* __restrict__ gamma,
    const float* __restrict__ fc, const float* __restrict__ fs,
    u16* __restrict__ kvpt,          // [S][544]
    float* __restrict__ kpe)         // [S][64]
{
  const int s = blockIdx.x, tid = threadIdx.x;
  const int wv = tid>>6, lane = tid&63;
  const u16* src = kvfull + (size_t)s*640;
  __shared__ float red1[4], red2[4];
  float v0 = bf2f(src[tid]), v1 = bf2f(src[tid+256]);
  float sq = v0*v0 + v1*v1;
  #pragma unroll
  for (int off=32; off; off>>=1) sq += __shfl_down(sq, off);
  if (lane==0) red1[wv]=sq;
  __syncthreads();
  float tot = red1[0]+red1[1]+red1[2]+red1[3];
  float rinv = 1.0f/sqrtf(tot*(1.0f/512.0f)+1e-6f);
  float n0 = v0*rinv*gamma[tid], n1 = v1*rinv*gamma[tid+256];
  float s2 = n0*n0+n1*n1;
  #pragma unroll
  for (int off=32; off; off>>=1) s2 += __shfl_down(s2, off);
  if (lane==0) red2[wv]=s2;
  __syncthreads();
  u16* dst = kvpt + (size_t)s*544;
  dst[1+tid]   = f2bf(n0);
  dst[257+tid] = f2bf(n1);
  if (tid==0) dst[0] = f2bf(sqrtf(red2[0]+red2[1]+red2[2]+red2[3]+1.0f));
  if (tid<31) dst[513+tid] = 0;
  if (tid<32){
    float x0 = bf2f(src[512+2*tid]), x1 = bf2f(src[513+2*tid]);
    float c = fc[(size_t)s*32+tid], sn = fs[(size_t)s*32+tid];
    kpe[(size_t)s*64 + 2*tid]   = x0*c - x1*sn;
    kpe[(size_t)s*64 + 2*tid+1] = x0*sn + x1*c;
  }
}

// ---------------- q_raw(bf16) -> rotary + Lorentz project (time NEGATED) ------
__global__ __launch_bounds__(64) void build_qproj(
    const u16* __restrict__ qraw,    // [S][3072]
    const float* __restrict__ fc, const float* __restrict__ fs,
    u16* __restrict__ qp)            // [NH][S][224]
{
  const int s = blockIdx.x, h = blockIdx.y, lane = threadIdx.x;
  const u16* src = qraw + (size_t)s*3072 + h*192;
  u16* dst = qp + ((size_t)h*S_LEN + s)*DPAD;
  u16 e0 = src[lane], e1 = src[lane+64];
  float f0 = bf2f(e0), f1 = bf2f(e1);
  dst[1+lane] = e0; dst[65+lane] = e1;
  float sq = f0*f0 + f1*f1;
  if (lane < 32){
    float x0 = bf2f(src[128+2*lane]), x1 = bf2f(src[129+2*lane]);
    float c = fc[(size_t)s*32+lane], sn = fs[(size_t)s*32+lane];
    float y0 = x0*c - x1*sn, y1 = x0*sn + x1*c;
    dst[129+2*lane] = f2bf(y0); dst[130+2*lane] = f2bf(y1);
    sq += y0*y0 + y1*y1;
  }
  if (lane < 31) dst[193+lane] = 0;
  #pragma unroll
  for (int off=32; off; off>>=1) sq += __shfl_down(sq, off);
  if (lane==0) dst[0] = f2bf(-sqrtf(sq+1.0f));   // Minkowski sign folded in
}

// ---------------- kvb(bf16) -> k_proj [NH][S][224], v_projT [NH][128][S] ------
__global__ __launch_bounds__(64) void build_kvproj(
    const u16* __restrict__ kvb,   // [S][4096], head h at cols h*255..+254
    const float* __restrict__ kpe,
    u16* __restrict__ kp,          // [NH][S][224]
    u16* __restrict__ vt)          // [NH][128][S]
{
  const int s = blockIdx.x, h = blockIdx.y, lane = threadIdx.x;
  const u16* src = kvb + (size_t)s*4096 + h*255;
  u16* kdst = kp + ((size_t)h*S_LEN + s)*DPAD;
  u16 a0 = src[lane], a1 = src[lane+64];
  float fa0 = bf2f(a0), fa1 = bf2f(a1);
  float pe = kpe[(size_t)s*64 + lane];
  kdst[1+lane] = a0; kdst[65+lane] = a1; kdst[129+lane] = f2bf(pe);
  if (lane<31) kdst[193+lane] = 0;
  float sq = fa0*fa0 + fa1*fa1 + pe*pe;
  #pragma unroll
  for (int off=32; off; off>>=1) sq += __shfl_down(sq, off);
  if (lane==0) kdst[0] = f2bf(sqrtf(sq+1.0f));
  u16 b0 = src[128+lane];
  u16 b1 = (lane<63) ? src[192+lane] : (u16)0;
  float fb0 = bf2f(b0), fb1 = bf2f(b1);
  u16* vbase = vt + (size_t)h*128*S_LEN;
  vbase[(size_t)(1+lane)*S_LEN + s] = b0;
  if (lane<63) vbase[(size_t)(65+lane)*S_LEN + s] = b1;
  float sv = fb0*fb0 + fb1*fb1;
  #pragma unroll
  for (int off=32; off; off>>=1) sv += __shfl_down(sv, off);
  if (lane==0) vbase[s] = f2bf(sqrtf(sv+1.0f));
}

// ---------------- key-split flash attention: partials ------------------------
// unit = (qt 64 q-rows, c 512-key chunk, h). 4 waves x 16 rows, 64-key tiles.
// Writes unnormalized O (f32) + (m,l) per row.
__global__ __launch_bounds__(256) void attn_part(
    const u16* __restrict__ qp,   // [NH][S][224] (time negated)
    const u16* __restrict__ kp,   // [NH][S][224]
    const u16* __restrict__ vt,   // [NH][128][S]
    const float* __restrict__ ss,
    float* __restrict__ Opart,    // [NH][32][4][64][128]
    float* __restrict__ ml)       // [NH][32][4][64][2]
{
  const int qt = blockIdx.x, c = blockIdx.y, h = blockIdx.z;
  if (c*CHUNK > qt*64 + 63) return;
  const int w = threadIdx.x>>6, lane = threadIdx.x&63;
  const int lg = lane>>4, li = lane&15;
  const int r0 = qt*64 + w*16;
  const float cl2 = (2.0f/ss[0]) * 1.44269504088896f;
  __shared__ __align__(16) u16 P[4][16][72];

  const u16* qb = qp + ((size_t)h*S_LEN + r0 + li)*DPAD + lg*8;
  bf16x8 qf[7];
  #pragma unroll
  for (int d=0; d<7; ++d) qf[d] = *(const bf16x8*)(qb + d*32);

  f32x4 of[8];
  #pragma unroll
  for (int d=0; d<8; ++d) of[d] = (f32x4){0.f,0.f,0.f,0.f};
  float mreg[4] = {-3e38f,-3e38f,-3e38f,-3e38f};
  float lreg[4] = {0.f,0.f,0.f,0.f};

  const int t0 = c*8;
  const int tE = min(c*8+7, (r0+15)>>6);
  for (int t=t0; t<=tE; ++t){
    const int k0 = t*64;
    const u16* kb = kp + ((size_t)h*S_LEN + k0 + li)*DPAD + lg*8;
    f32x4 s[4];
    #pragma unroll
    for (int j=0;j<4;++j) s[j] = (f32x4){0.f,0.f,0.f,0.f};
    #pragma unroll
    for (int d=0; d<7; ++d){
      #pragma unroll
      for (int j=0;j<4;++j){
        bf16x8 kf = *(const bf16x8*)(kb + j*16*DPAD + d*32);
        s[j] = __builtin_amdgcn_mfma_f32_16x16x32_bf16(qf[d], kf, s[j], 0,0,0);
      }
    }
    // prefetch V low half (keys k0..k0+31) — hides L2 latency under softmax
    const u16* vb = vt + ((size_t)h*128 + li)*S_LEN + k0 + lg*8;
    bf16x8 vlo[8];
    #pragma unroll
    for (int d=0;d<8;++d) vlo[d] = *(const bf16x8*)(vb + (size_t)d*16*S_LEN);

    float alpha[4];
    #pragma unroll
    for (int r=0;r<4;++r){
      const int row = r0 + lg*4 + r;
      float a0 = (k0 + li      <= row) ? s[0][r] : -3e38f;
      float a1 = (k0 + 16 + li <= row) ? s[1][r] : -3e38f;
      float a2 = (k0 + 32 + li <= row) ? s[2][r] : -3e38f;
      float a3 = (k0 + 48 + li <= row) ? s[3][r] : -3e38f;
      float mx = fmaxf(fmaxf(a0,a1), fmaxf(a2,a3));
      mx = fmaxf(mx, __shfl_xor(mx,1));
      mx = fmaxf(mx, __shfl_xor(mx,2));
      mx = fmaxf(mx, __shfl_xor(mx,4));
      mx = fmaxf(mx, __shfl_xor(mx,8));
      float mn = fmaxf(mreg[r], mx);
      alpha[r] = exp2f((mreg[r]-mn)*cl2);
      mreg[r] = mn;
      float e0 = exp2f((a0-mn)*cl2);
      float e1 = exp2f((a1-mn)*cl2);
      float e2 = exp2f((a2-mn)*cl2);
      float e3 = exp2f((a3-mn)*cl2);
      float ls = (e0+e1)+(e2+e3);
      ls += __shfl_xor(ls,1);
      ls += __shfl_xor(ls,2);
      ls += __shfl_xor(ls,4);
      ls += __shfl_xor(ls,8);
      lreg[r] = lreg[r]*alpha[r] + ls;
      P[w][lg*4+r][li]    = f2bf(e0);
      P[w][lg*4+r][li+16] = f2bf(e1);
      P[w][lg*4+r][li+32] = f2bf(e2);
      P[w][lg*4+r][li+48] = f2bf(e3);
    }
    #pragma unroll
    for (int d=0;d<8;++d){
      of[d][0]*=alpha[0]; of[d][1]*=alpha[1];
      of[d][2]*=alpha[2]; of[d][3]*=alpha[3];
    }
    bf16x8 pa0 = *(const bf16x8*)(&P[w][li][lg*8]);
    bf16x8 pa1 = *(const bf16x8*)(&P[w][li][32+lg*8]);
    #pragma unroll
    for (int d=0;d<8;++d){
      bf16x8 vhi = *(const bf16x8*)(vb + (size_t)d*16*S_LEN + 32);
      of[d] = __builtin_amdgcn_mfma_f32_16x16x32_bf16(pa0, vlo[d], of[d], 0,0,0);
      of[d] = __builtin_amdgcn_mfma_f32_16x16x32_bf16(pa1, vhi,    of[d], 0,0,0);
    }
  }
  // store partials (unconditional — empty waves write m=-3e38, l=0, O=0)
  const int slot = (h*32 + qt)*4 + c;
  float* ob = Opart + (size_t)slot*8192;
  #pragma unroll
  for (int r=0;r<4;++r){
    const int rw = w*16 + lg*4 + r;
    #pragma unroll
    for (int d=0;d<8;++d) ob[(size_t)rw*128 + d*16 + li] = of[d][r];
    if (li == 0){
      ml[((size_t)slot*64 + rw)*2]   = mreg[r];
      ml[((size_t)slot*64 + rw)*2+1] = lreg[r];
    }
  }
}

// ---------------- combine partials + Lorentz centroid epilogue ----------------
__global__ __launch_bounds__(256) void attn_combine(
    const float* __restrict__ Opart, const float* __restrict__ ml,
    const float* __restrict__ ss, u16* __restrict__ out)  // [S][2048] bf16
{
  const int qt = blockIdx.x, h = blockIdx.y;
  const int nc = (qt>>3) + 1;
  const int tid = threadIdx.x;
  const int row = tid >> 2;        // 0..63
  const int sub = tid & 3;         // cols sub*32..sub*32+31
  const float cl2 = (2.0f/ss[0]) * 1.44269504088896f;
  const size_t slotbase = ((size_t)h*32 + qt)*4;

  float m[4], l[4];
  float mstar = -3e38f;
  #pragma unroll
  for (int c=0;c<4;++c){
    float2 v = *(const float2*)(ml + (slotbase + c)*128 + row*2);
    m[c] = (c < nc) ? v.x : -3e38f;
    l[c] = (c < nc) ? v.y : 0.f;
    mstar = fmaxf(mstar, m[c]);
  }
  float lstar = 0.f; float wgt[4];
  #pragma unroll
  for (int c=0;c<4;++c){ wgt[c] = exp2f((m[c]-mstar)*cl2); lstar += l[c]*wgt[c]; }
  float linv = 1.0f/lstar;

  float av[32];
  float part = 0.f;
  #pragma unroll
  for (int i=0;i<8;++i){
    float o0=0.f,o1=0.f,o2=0.f,o3=0.f;
    #pragma unroll
    for (int c=0;c<4;++c){
      float4 p = *(const float4*)(Opart + (slotbase+c)*8192 + row*128 + sub*32 + i*4);
      o0 += p.x*wgt[c]; o1 += p.y*wgt[c]; o2 += p.z*wgt[c]; o3 += p.w*wgt[c];
    }
    float a0=o0*linv, a1=o1*linv, a2=o2*linv, a3=o3*linv;
    av[i*4]=a0; av[i*4+1]=a1; av[i*4+2]=a2; av[i*4+3]=a3;
    part += a0*a0 + a1*a1 + a2*a2 + a3*a3;
  }
  if (sub==0) part -= 2.f*av[0]*av[0];    // col 0 = time component
  part += __shfl_xor(part,1);
  part += __shfl_xor(part,2);
  float sc = 1.0f/sqrtf(fmaxf(fabsf(part),1e-8f));
  u16* ob = out + (size_t)(qt*64+row)*2048 + h*128 + sub*32;
  #pragma unroll
  for (int i=0;i<32;++i) ob[i] = f2bf(av[i]*sc);
}

// ---------------- final projection: out = [sqrt(|y|^2+1), y] (f32 out) --------
__global__ __launch_bounds__(256) void final_project(
    const u16* __restrict__ y,  // [S][2048], cols 0..2046 valid
    float* __restrict__ out)    // [S][2048]
{
  const int s = blockIdx.x, tid = threadIdx.x;
  const int wv = tid>>6, lane = tid&63;
  const u16* src = y + (size_t)s*2048;
  float* dst = out + (size_t)s*2048;
  float sq = 0.f;
  for (int j=tid; j<2047; j+=256){
    float v = bf2f(src[j]);
    dst[1+j] = v;
    sq += v*v;
  }
  __shared__ float red[4];
  #pragma unroll
  for (int off=32; off; off>>=1) sq += __shfl_down(sq, off);
  if (lane==0) red[wv]=sq;
  __syncthreads();
  if (tid==0) dst[0] = sqrtf(red[0]+red[1]+red[2]+red[3]+1.0f);
}

extern "C" void kernel_launch(void* const* d_in, const int* in_sizes, int n_in,
                              void* d_out, int out_size, void* d_ws, size_t ws_size,
                              hipStream_t stream) {
  const float* x    = (const float*)d_in[0];
  const float* fc   = (const float*)d_in[2];
  const float* fs   = (const float*)d_in[3];
  const float* wq   = (const float*)d_in[5];
  const float* wkva = (const float*)d_in[6];
  const float* gam  = (const float*)d_in[7];
  const float* wkvb = (const float*)d_in[8];
  const float* wo   = (const float*)d_in[9];
  const float* ssp  = (const float*)d_in[10];
  float* out = (float*)d_out;
  char* base = (char*)d_ws;

  // Region A (reused 3x), peak total 114 MB:
  u16*   xb     = (u16*)(base + 0);           // [2048][2048] bf16
  u16*   wqT    = (u16*)(base + 8388608);     // [3072][2048]
  u16*   wkvaT  = (u16*)(base + 20971520);    // [640][2048]
  u16*   wkvbT  = (u16*)(base + 23592960);    // [4096][544]
  u16*   kvfull = (u16*)(base + 28049408);    // [2048][640]
  u16*   kvpt   = (u16*)(base + 30670848);    // [2048][544]
  float* kpe    = (float*)(base + 32899072);  // [2048][64]
  u16*   kvb    = (u16*)(base + 33423360);    // [2048][4096]
  float* Opart  = (float*)(base + 0);         // [16][32][4][64][128] (A dead)
  float* mlbuf  = (float*)(base + 67108864);  // [16][32][4][64][2]
  u16*   woT    = (u16*)(base + 0);           // [2048][2048] (Opart dead)
  u16*   yb     = (u16*)(base + 16777216);    // [2048][2048]
  // Region B:
  u16*   qraw   = (u16*)(base + 69206016);    // [2048][3072] -> attn_o [2048][2048]
  // Region C:
  u16*   qproj  = (u16*)(base + 81788928);    // [16][2048][224]
  u16*   kproj  = (u16*)(base + 96468992);    // [16][2048][224]
  u16*   vprojT = (u16*)(base + 111149056);   // [16][128][2048]
  u16*   attn_o = qraw;

  dim3 tb(32,8);
  cast_bf16x8<<<2048, 256, 0, stream>>>(x, xb);
  transpose_cast<<<dim3(64,96),  tb, 0, stream>>>(wq,   wqT,   2048, 3072, 3072, 2048);
  transpose_cast<<<dim3(64,20),  tb, 0, stream>>>(wkva, wkvaT, 2048,  576,  640, 2048);
  gemm_bf16<<<dim3(24,16), 256, 0, stream>>>(xb, wqT,   qraw,   2048, 3072, 2048);
  gemm_bf16<<<dim3(5,16),  256, 0, stream>>>(xb, wkvaT, kvfull, 2048,  640, 2048);
  build_kvpt<<<2048, 256, 0, stream>>>(kvfull, gam, fc, fs, kvpt, kpe);
  transpose_cast<<<dim3(17,128), tb, 0, stream>>>(wkvb, wkvbT,  513, 4080, 4096,  544);
  gemm_bf16<<<dim3(32,16), 256, 0, stream>>>(kvpt, wkvbT, kvb,  2048, 4096,  544);
  build_qproj<<<dim3(2048,16), 64, 0, stream>>>(qraw, fc, fs, qproj);
  build_kvproj<<<dim3(2048,16), 64, 0, stream>>>(kvb, kpe, kproj, vprojT);
  attn_part<<<dim3(32,4,16), 256, 0, stream>>>(qproj, kproj, vprojT, ssp, Opart, mlbuf);
  attn_combine<<<dim3(32,16), 256, 0, stream>>>(Opart, mlbuf, ssp, attn_o);
  transpose_cast<<<dim3(64,64), tb, 0, stream>>>(wo, woT, 2048, 2047, 2048, 2048);
  gemm_bf16<<<dim3(16,16), 256, 0, stream>>>(attn_o, woT, yb, 2048, 2048, 2048);
  final_project<<<2048, 256, 0, stream>>>(yb, out);
}

// Round 4
// 564.876 us; speedup vs baseline: 1.0873x; 1.0873x over previous
//
#include <hip/hip_runtime.h>
#include <math.h>

// LorentzMLA — bf16 MFMA implementation, key-split flash attention.
// Round 4: (1) h-fastest 1-D attn grid -> head pinned to XCD -> K/V L2-resident;
//          (2) GEMM staged via global_load_lds (m97 structure).

typedef unsigned short u16;
typedef unsigned int u32;
typedef __attribute__((ext_vector_type(8))) short bf16x8;
typedef __attribute__((ext_vector_type(4))) float f32x4;

#define S_LEN 2048
#define NH 16
#define DPAD 224
#define CHUNK 512

#define GLOAD16(g, l) __builtin_amdgcn_global_load_lds( \
    (const __attribute__((address_space(1))) void*)(g), \
    (__attribute__((address_space(3))) void*)(l), 16, 0, 0)

__device__ __forceinline__ u16 f2bf(float f){
  u32 u = __builtin_bit_cast(u32, f);
  u32 r = u + 0x7fffu + ((u >> 16) & 1u);
  return (u16)(r >> 16);
}
__device__ __forceinline__ float bf2f(u16 h){
  u32 u = ((u32)h) << 16;
  return __builtin_bit_cast(float, u);
}

// ---------------- f32 -> bf16 cast, 8 elems/thread ----------------------------
__global__ __launch_bounds__(256) void cast_bf16x8(
    const float* __restrict__ in, u16* __restrict__ out)
{
  size_t i = ((size_t)blockIdx.x*256 + threadIdx.x)*8;
  float4 a = *(const float4*)(in + i);
  float4 b = *(const float4*)(in + i + 4);
  uint4 v;
  v.x = (u32)f2bf(a.x) | ((u32)f2bf(a.y) << 16);
  v.y = (u32)f2bf(a.z) | ((u32)f2bf(a.w) << 16);
  v.z = (u32)f2bf(b.x) | ((u32)f2bf(b.y) << 16);
  v.w = (u32)f2bf(b.z) | ((u32)f2bf(b.w) << 16);
  *(uint4*)(out + i) = v;
}

// ---------------- transpose + cast + zero-pad: out[n][k] = in[k][n] -----------
__global__ void transpose_cast(const float* __restrict__ in, u16* __restrict__ out,
                               int R, int Cc, int outR, int outC)
{
  __shared__ float t[32][33];
  const int tx = threadIdx.x, ty = threadIdx.y;
  const int bx = blockIdx.x*32, by = blockIdx.y*32;
  #pragma unroll
  for (int i=0;i<4;++i){
    int r = bx + ty + i*8, c = by + tx;
    t[ty+i*8][tx] = (r<R && c<Cc) ? in[(size_t)r*Cc + c] : 0.f;
  }
  __syncthreads();
  #pragma unroll
  for (int i=0;i<4;++i){
    int orow = by + ty + i*8, ocol = bx + tx;
    if (orow<outR && ocol<outC) out[(size_t)orow*outC + ocol] = f2bf(t[tx][ty+i*8]);
  }
}

// ---------------- bf16 MFMA GEMM: C[M][N] = A[M][K] @ BT[N][K]^T ---------------
// 128x128 tile, BK=32, 4 waves; global_load_lds staging (m97 structure).
__global__ __launch_bounds__(256) void gemm_bf16(
    const u16* __restrict__ A, const u16* __restrict__ BT, u16* __restrict__ C,
    int M, int N, int K)
{
  __shared__ __align__(16) u16 As[128*32];
  __shared__ __align__(16) u16 Bs[128*32];
  const int tid = threadIdx.x;
  const int bm = blockIdx.y*128, bn = blockIdx.x*128;
  const int w = tid>>6, lane = tid&63, lg = lane>>4, li = lane&15;
  const int wr = w>>1, wc = w&1;

  // staging: wave w covers rows [w*32, w*32+32) of A and of B (2 wave-loads each)
  const u16* Asrc = A  + (size_t)(bm + w*32 + (lane>>2))*K + (lane&3)*8;
  const u16* Bsrc = BT + (size_t)(bn + w*32 + (lane>>2))*K + (lane&3)*8;
  u16* Adst = As + w*32*32;      // HW adds lane*16B
  u16* Bdst = Bs + w*32*32;
  const u16* ar = &As[(wr*64+li)*32 + lg*8];
  const u16* br = &Bs[(wc*64+li)*32 + lg*8];

  f32x4 acc[4][4];
  #pragma unroll
  for (int m=0;m<4;++m)
    #pragma unroll
    for (int n=0;n<4;++n) acc[m][n] = (f32x4){0.f,0.f,0.f,0.f};

  const int nk = K >> 5;
  for (int kt=0; kt<nk; ++kt){
    const int ko = kt*32;
    GLOAD16(Asrc + ko,            Adst);
    GLOAD16(Asrc + ko + 16*(size_t)K, Adst + 16*32);
    GLOAD16(Bsrc + ko,            Bdst);
    GLOAD16(Bsrc + ko + 16*(size_t)K, Bdst + 16*32);
    asm volatile("s_waitcnt vmcnt(0)" ::: "memory");
    __syncthreads();
    bf16x8 af[4], bg[4];
    #pragma unroll
    for (int m=0;m<4;++m) af[m] = *(const bf16x8*)(ar + m*16*32);
    #pragma unroll
    for (int n=0;n<4;++n) bg[n] = *(const bf16x8*)(br + n*16*32);
    #pragma unroll
    for (int m=0;m<4;++m)
      #pragma unroll
      for (int n=0;n<4;++n)
        acc[m][n] = __builtin_amdgcn_mfma_f32_16x16x32_bf16(af[m], bg[n], acc[m][n], 0,0,0);
    __syncthreads();
  }
  #pragma unroll
  for (int m=0;m<4;++m){
    const int row = bm + wr*64 + m*16 + lg*4;
    #pragma unroll
    for (int n=0;n<4;++n){
      const int col = bn + wc*64 + n*16 + li;
      #pragma unroll
      for (int r=0;r<4;++r)
        C[(size_t)(row+r)*N + col] = f2bf(acc[m][n][r]);
    }
  }
}

// ---------------- kv_full(bf16) -> rmsnorm+project kv_pt(bf16 pad), rotary k_pe
__global__ __launch_bounds__(256) void build_kvpt(
    const u16* __restrict__ kvfull,  // [S][640], cols 0..575 valid
    const float* __restrict__ gamma,
    const float* __restrict__ fc, const float* __restrict__ fs,
    u16* __restrict__ kvpt,          // [S][544]
    float* __restrict__ kpe)         // [S][64]
{
  const int s = blockIdx.x, tid = threadIdx.x;
  const int wv = tid>>6, lane = tid&63;
  const u16* src = kvfull + (size_t)s*640;
  __shared__ float red1[4], red2[4];
  float v0 = bf2f(src[tid]), v1 = bf2f(src[tid+256]);
  float sq = v0*v0 + v1*v1;
  #pragma unroll
  for (int off=32; off; off>>=1) sq += __shfl_down(sq, off);
  if (lane==0) red1[wv]=sq;
  __syncthreads();
  float tot = red1[0]+red1[1]+red1[2]+red1[3];
  float rinv = 1.0f/sqrtf(tot*(1.0f/512.0f)+1e-6f);
  float n0 = v0*rinv*gamma[tid], n1 = v1*rinv*gamma[tid+256];
  float s2 = n0*n0+n1*n1;
  #pragma unroll
  for (int off=32; off; off>>=1) s2 += __shfl_down(s2, off);
  if (lane==0) red2[wv]=s2;
  __syncthreads();
  u16* dst = kvpt + (size_t)s*544;
  dst[1+tid]   = f2bf(n0);
  dst[257+tid] = f2bf(n1);
  if (tid==0) dst[0] = f2bf(sqrtf(red2[0]+red2[1]+red2[2]+red2[3]+1.0f));
  if (tid<31) dst[513+tid] = 0;
  if (tid<32){
    float x0 = bf2f(src[512+2*tid]), x1 = bf2f(src[513+2*tid]);
    float c = fc[(size_t)s*32+tid], sn = fs[(size_t)s*32+tid];
    kpe[(size_t)s*64 + 2*tid]   = x0*c - x1*sn;
    kpe[(size_t)s*64 + 2*tid+1] = x0*sn + x1*c;
  }
}

// ---------------- q_raw(bf16) -> rotary + Lorentz project (time NEGATED) ------
__global__ __launch_bounds__(64) void build_qproj(
    const u16* __restrict__ qraw,    // [S][3072]
    const float* __restrict__ fc, const float* __restrict__ fs,
    u16* __restrict__ qp)            // [NH][S][224]
{
  const int s = blockIdx.x, h = blockIdx.y, lane = threadIdx.x;
  const u16* src = qraw + (size_t)s*3072 + h*192;
  u16* dst = qp + ((size_t)h*S_LEN + s)*DPAD;
  u16 e0 = src[lane], e1 = src[lane+64];
  float f0 = bf2f(e0), f1 = bf2f(e1);
  dst[1+lane] = e0; dst[65+lane] = e1;
  float sq = f0*f0 + f1*f1;
  if (lane < 32){
    float x0 = bf2f(src[128+2*lane]), x1 = bf2f(src[129+2*lane]);
    float c = fc[(size_t)s*32+lane], sn = fs[(size_t)s*32+lane];
    float y0 = x0*c - x1*sn, y1 = x0*sn + x1*c;
    dst[129+2*lane] = f2bf(y0); dst[130+2*lane] = f2bf(y1);
    sq += y0*y0 + y1*y1;
  }
  if (lane < 31) dst[193+lane] = 0;
  #pragma unroll
  for (int off=32; off; off>>=1) sq += __shfl_down(sq, off);
  if (lane==0) dst[0] = f2bf(-sqrtf(sq+1.0f));   // Minkowski sign folded in
}

// ---------------- kvb(bf16) -> k_proj [NH][S][224], v_projT [NH][128][S] ------
__global__ __launch_bounds__(64) void build_kvproj(
    const u16* __restrict__ kvb,   // [S][4096], head h at cols h*255..+254
    const float* __restrict__ kpe,
    u16* __restrict__ kp,          // [NH][S][224]
    u16* __restrict__ vt)          // [NH][128][S]
{
  const int s = blockIdx.x, h = blockIdx.y, lane = threadIdx.x;
  const u16* src = kvb + (size_t)s*4096 + h*255;
  u16* kdst = kp + ((size_t)h*S_LEN + s)*DPAD;
  u16 a0 = src[lane], a1 = src[lane+64];
  float fa0 = bf2f(a0), fa1 = bf2f(a1);
  float pe = kpe[(size_t)s*64 + lane];
  kdst[1+lane] = a0; kdst[65+lane] = a1; kdst[129+lane] = f2bf(pe);
  if (lane<31) kdst[193+lane] = 0;
  float sq = fa0*fa0 + fa1*fa1 + pe*pe;
  #pragma unroll
  for (int off=32; off; off>>=1) sq += __shfl_down(sq, off);
  if (lane==0) kdst[0] = f2bf(sqrtf(sq+1.0f));
  u16 b0 = src[128+lane];
  u16 b1 = (lane<63) ? src[192+lane] : (u16)0;
  float fb0 = bf2f(b0), fb1 = bf2f(b1);
  u16* vbase = vt + (size_t)h*128*S_LEN;
  vbase[(size_t)(1+lane)*S_LEN + s] = b0;
  if (lane<63) vbase[(size_t)(65+lane)*S_LEN + s] = b1;
  float sv = fb0*fb0 + fb1*fb1;
  #pragma unroll
  for (int off=32; off; off>>=1) sv += __shfl_down(sv, off);
  if (lane==0) vbase[s] = f2bf(sqrtf(sv+1.0f));
}

// ---------------- key-split flash attention: partials ------------------------
// 1-D grid, h fastest (h%8 pins head to one XCD -> K/V L2-resident),
// qt descending (heavy blocks dispatch first).
__global__ __launch_bounds__(256) void attn_part(
    const u16* __restrict__ qp,   // [NH][S][224] (time negated)
    const u16* __restrict__ kp,   // [NH][S][224]
    const u16* __restrict__ vt,   // [NH][128][S]
    const float* __restrict__ ss,
    float* __restrict__ Opart,    // [NH][32][4][64][128]
    float* __restrict__ ml)       // [NH][32][4][64][2]
{
  const int h  = blockIdx.x & 15;
  const int rr = blockIdx.x >> 4;      // 0..127
  const int qt = 31 - (rr & 31);
  const int c  = rr >> 5;              // 0..3
  if (c*CHUNK > qt*64 + 63) return;
  const int w = threadIdx.x>>6, lane = threadIdx.x&63;
  const int lg = lane>>4, li = lane&15;
  const int r0 = qt*64 + w*16;
  const float cl2 = (2.0f/ss[0]) * 1.44269504088896f;
  __shared__ __align__(16) u16 P[4][16][72];

  const u16* qb = qp + ((size_t)h*S_LEN + r0 + li)*DPAD + lg*8;
  bf16x8 qf[7];
  #pragma unroll
  for (int d=0; d<7; ++d) qf[d] = *(const bf16x8*)(qb + d*32);

  f32x4 of[8];
  #pragma unroll
  for (int d=0; d<8; ++d) of[d] = (f32x4){0.f,0.f,0.f,0.f};
  float mreg[4] = {-3e38f,-3e38f,-3e38f,-3e38f};
  float lreg[4] = {0.f,0.f,0.f,0.f};

  const int t0 = c*8;
  const int tE = min(c*8+7, (r0+15)>>6);
  for (int t=t0; t<=tE; ++t){
    const int k0 = t*64;
    const u16* kb = kp + ((size_t)h*S_LEN + k0 + li)*DPAD + lg*8;
    f32x4 s[4];
    #pragma unroll
    for (int j=0;j<4;++j) s[j] = (f32x4){0.f,0.f,0.f,0.f};
    #pragma unroll
    for (int d=0; d<7; ++d){
      #pragma unroll
      for (int j=0;j<4;++j){
        bf16x8 kf = *(const bf16x8*)(kb + j*16*DPAD + d*32);
        s[j] = __builtin_amdgcn_mfma_f32_16x16x32_bf16(qf[d], kf, s[j], 0,0,0);
      }
    }
    // prefetch V low half — hides latency under softmax
    const u16* vb = vt + ((size_t)h*128 + li)*S_LEN + k0 + lg*8;
    bf16x8 vlo[8];
    #pragma unroll
    for (int d=0;d<8;++d) vlo[d] = *(const bf16x8*)(vb + (size_t)d*16*S_LEN);

    float alpha[4];
    #pragma unroll
    for (int r=0;r<4;++r){
      const int row = r0 + lg*4 + r;
      float a0 = (k0 + li      <= row) ? s[0][r] : -3e38f;
      float a1 = (k0 + 16 + li <= row) ? s[1][r] : -3e38f;
      float a2 = (k0 + 32 + li <= row) ? s[2][r] : -3e38f;
      float a3 = (k0 + 48 + li <= row) ? s[3][r] : -3e38f;
      float mx = fmaxf(fmaxf(a0,a1), fmaxf(a2,a3));
      mx = fmaxf(mx, __shfl_xor(mx,1));
      mx = fmaxf(mx, __shfl_xor(mx,2));
      mx = fmaxf(mx, __shfl_xor(mx,4));
      mx = fmaxf(mx, __shfl_xor(mx,8));
      float mn = fmaxf(mreg[r], mx);
      alpha[r] = exp2f((mreg[r]-mn)*cl2);
      mreg[r] = mn;
      float e0 = exp2f((a0-mn)*cl2);
      float e1 = exp2f((a1-mn)*cl2);
      float e2 = exp2f((a2-mn)*cl2);
      float e3 = exp2f((a3-mn)*cl2);
      float ls = (e0+e1)+(e2+e3);
      ls += __shfl_xor(ls,1);
      ls += __shfl_xor(ls,2);
      ls += __shfl_xor(ls,4);
      ls += __shfl_xor(ls,8);
      lreg[r] = lreg[r]*alpha[r] + ls;
      P[w][lg*4+r][li]    = f2bf(e0);
      P[w][lg*4+r][li+16] = f2bf(e1);
      P[w][lg*4+r][li+32] = f2bf(e2);
      P[w][lg*4+r][li+48] = f2bf(e3);
    }
    #pragma unroll
    for (int d=0;d<8;++d){
      of[d][0]*=alpha[0]; of[d][1]*=alpha[1];
      of[d][2]*=alpha[2]; of[d][3]*=alpha[3];
    }
    bf16x8 pa0 = *(const bf16x8*)(&P[w][li][lg*8]);
    bf16x8 pa1 = *(const bf16x8*)(&P[w][li][32+lg*8]);
    #pragma unroll
    for (int d=0;d<8;++d){
      bf16x8 vhi = *(const bf16x8*)(vb + (size_t)d*16*S_LEN + 32);
      of[d] = __builtin_amdgcn_mfma_f32_16x16x32_bf16(pa0, vlo[d], of[d], 0,0,0);
      of[d] = __builtin_amdgcn_mfma_f32_16x16x32_bf16(pa1, vhi,    of[d], 0,0,0);
    }
  }
  const int slot = (h*32 + qt)*4 + c;
  float* ob = Opart + (size_t)slot*8192;
  #pragma unroll
  for (int r=0;r<4;++r){
    const int rw = w*16 + lg*4 + r;
    #pragma unroll
    for (int d=0;d<8;++d) ob[(size_t)rw*128 + d*16 + li] = of[d][r];
    if (li == 0){
      ml[((size_t)slot*64 + rw)*2]   = mreg[r];
      ml[((size_t)slot*64 + rw)*2+1] = lreg[r];
    }
  }
}

// ---------------- combine partials + Lorentz centroid epilogue ----------------
__global__ __launch_bounds__(256) void attn_combine(
    const float* __restrict__ Opart, const float* __restrict__ ml,
    const float* __restrict__ ss, u16* __restrict__ out)  // [S][2048] bf16
{
  const int h = blockIdx.x & 15;
  const int qt = blockIdx.x >> 4;
  const int nc = (qt>>3) + 1;
  const int tid = threadIdx.x;
  const int row = tid >> 2;        // 0..63
  const int sub = tid & 3;         // cols sub*32..sub*32+31
  const float cl2 = (2.0f/ss[0]) * 1.44269504088896f;
  const size_t slotbase = ((size_t)h*32 + qt)*4;

  float m[4], l[4];
  float mstar = -3e38f;
  #pragma unroll
  for (int c=0;c<4;++c){
    float2 v = *(const float2*)(ml + (slotbase + c)*128 + row*2);
    m[c] = (c < nc) ? v.x : -3e38f;
    l[c] = (c < nc) ? v.y : 0.f;
    mstar = fmaxf(mstar, m[c]);
  }
  float lstar = 0.f; float wgt[4];
  #pragma unroll
  for (int c=0;c<4;++c){ wgt[c] = exp2f((m[c]-mstar)*cl2); lstar += l[c]*wgt[c]; }
  float linv = 1.0f/lstar;

  float av[32];
  float part = 0.f;
  #pragma unroll
  for (int i=0;i<8;++i){
    float o0=0.f,o1=0.f,o2=0.f,o3=0.f;
    #pragma unroll
    for (int c=0;c<4;++c){
      float4 p = *(const float4*)(Opart + (slotbase+c)*8192 + row*128 + sub*32 + i*4);
      o0 += p.x*wgt[c]; o1 += p.y*wgt[c]; o2 += p.z*wgt[c]; o3 += p.w*wgt[c];
    }
    float a0=o0*linv, a1=o1*linv, a2=o2*linv, a3=o3*linv;
    av[i*4]=a0; av[i*4+1]=a1; av[i*4+2]=a2; av[i*4+3]=a3;
    part += a0*a0 + a1*a1 + a2*a2 + a3*a3;
  }
  if (sub==0) part -= 2.f*av[0]*av[0];    // col 0 = time component
  part += __shfl_xor(part,1);
  part += __shfl_xor(part,2);
  float sc = 1.0f/sqrtf(fmaxf(fabsf(part),1e-8f));
  u16* ob = out + (size_t)(qt*64+row)*2048 + h*128 + sub*32;
  #pragma unroll
  for (int i=0;i<32;++i) ob[i] = f2bf(av[i]*sc);
}

// ---------------- final projection: out = [sqrt(|y|^2+1), y] (f32 out) --------
__global__ __launch_bounds__(256) void final_project(
    const u16* __restrict__ y,  // [S][2048], cols 0..2046 valid
    float* __restrict__ out)    // [S][2048]
{
  const int s = blockIdx.x, tid = threadIdx.x;
  const int wv = tid>>6, lane = tid&63;
  const u16* src = y + (size_t)s*2048;
  float* dst = out + (size_t)s*2048;
  float sq = 0.f;
  for (int j=tid; j<2047; j+=256){
    float v = bf2f(src[j]);
    dst[1+j] = v;
    sq += v*v;
  }
  __shared__ float red[4];
  #pragma unroll
  for (int off=32; off; off>>=1) sq += __shfl_down(sq, off);
  if (lane==0) red[wv]=sq;
  __syncthreads();
  if (tid==0) dst[0] = sqrtf(red[0]+red[1]+red[2]+red[3]+1.0f);
}

extern "C" void kernel_launch(void* const* d_in, const int* in_sizes, int n_in,
                              void* d_out, int out_size, void* d_ws, size_t ws_size,
                              hipStream_t stream) {
  const float* x    = (const float*)d_in[0];
  const float* fc   = (const float*)d_in[2];
  const float* fs   = (const float*)d_in[3];
  const float* wq   = (const float*)d_in[5];
  const float* wkva = (const float*)d_in[6];
  const float* gam  = (const float*)d_in[7];
  const float* wkvb = (const float*)d_in[8];
  const float* wo   = (const float*)d_in[9];
  const float* ssp  = (const float*)d_in[10];
  float* out = (float*)d_out;
  char* base = (char*)d_ws;

  // Region A (reused 3x), peak total 114 MB:
  u16*   xb     = (u16*)(base + 0);           // [2048][2048] bf16
  u16*   wqT    = (u16*)(base + 8388608);     // [3072][2048]
  u16*   wkvaT  = (u16*)(base + 20971520);    // [640][2048]
  u16*   wkvbT  = (u16*)(base + 23592960);    // [4096][544]
  u16*   kvfull = (u16*)(base + 28049408);    // [2048][640]
  u16*   kvpt   = (u16*)(base + 30670848);    // [2048][544]
  float* kpe    = (float*)(base + 32899072);  // [2048][64]
  u16*   kvb    = (u16*)(base + 33423360);    // [2048][4096]
  float* Opart  = (float*)(base + 0);         // [16][32][4][64][128] (A dead)
  float* mlbuf  = (float*)(base + 67108864);  // [16][32][4][64][2]
  u16*   woT    = (u16*)(base + 0);           // [2048][2048] (Opart dead)
  u16*   yb     = (u16*)(base + 16777216);    // [2048][2048]
  // Region B:
  u16*   qraw   = (u16*)(base + 69206016);    // [2048][3072] -> attn_o [2048][2048]
  // Region C:
  u16*   qproj  = (u16*)(base + 81788928);    // [16][2048][224]
  u16*   kproj  = (u16*)(base + 96468992);    // [16][2048][224]
  u16*   vprojT = (u16*)(base + 111149056);   // [16][128][2048]
  u16*   attn_o = qraw;

  dim3 tb(32,8);
  cast_bf16x8<<<2048, 256, 0, stream>>>(x, xb);
  transpose_cast<<<dim3(64,96),  tb, 0, stream>>>(wq,   wqT,   2048, 3072, 3072, 2048);
  transpose_cast<<<dim3(64,20),  tb, 0, stream>>>(wkva, wkvaT, 2048,  576,  640, 2048);
  gemm_bf16<<<dim3(24,16), 256, 0, stream>>>(xb, wqT,   qraw,   2048, 3072, 2048);
  gemm_bf16<<<dim3(5,16),  256, 0, stream>>>(xb, wkvaT, kvfull, 2048,  640, 2048);
  build_kvpt<<<2048, 256, 0, stream>>>(kvfull, gam, fc, fs, kvpt, kpe);
  transpose_cast<<<dim3(17,128), tb, 0, stream>>>(wkvb, wkvbT,  513, 4080, 4096,  544);
  gemm_bf16<<<dim3(32,16), 256, 0, stream>>>(kvpt, wkvbT, kvb,  2048, 4096,  544);
  build_qproj<<<dim3(2048,16), 64, 0, stream>>>(qraw, fc, fs, qproj);
  build_kvproj<<<dim3(2048,16), 64, 0, stream>>>(kvb, kpe, kproj, vprojT);
  attn_part<<<2048, 256, 0, stream>>>(qproj, kproj, vprojT, ssp, Opart, mlbuf);
  attn_combine<<<512, 256, 0, stream>>>(Opart, mlbuf, ssp, attn_o);
  transpose_cast<<<dim3(64,64), tb, 0, stream>>>(wo, woT, 2048, 2047, 2048, 2048);
  gemm_bf16<<<dim3(16,16), 256, 0, stream>>>(attn_o, woT, yb, 2048, 2048, 2048);
  final_project<<<2048, 256, 0, stream>>>(yb, out);
}

// Round 5
// 484.150 us; speedup vs baseline: 1.2686x; 1.1667x over previous
//
#include <hip/hip_runtime.h>
#include <math.h>

// LorentzMLA — bf16 MFMA implementation.
// Round 5: attention decomposed into UNIFORM wave-independent units
//   (head, 16-row strip, 256-key chunk) -> 9216 units, no empty waves,
//   h fastest for XCD pinning. GEMM reverted to reg-prefetch (round-3) form.

typedef unsigned short u16;
typedef unsigned int u32;
typedef __attribute__((ext_vector_type(8))) short bf16x8;
typedef __attribute__((ext_vector_type(4))) float f32x4;

#define S_LEN 2048
#define NH 16
#define DPAD 224

__device__ __forceinline__ u16 f2bf(float f){
  u32 u = __builtin_bit_cast(u32, f);
  u32 r = u + 0x7fffu + ((u >> 16) & 1u);
  return (u16)(r >> 16);
}
__device__ __forceinline__ float bf2f(u16 h){
  u32 u = ((u32)h) << 16;
  return __builtin_bit_cast(float, u);
}

// ---------------- f32 -> bf16 cast, 8 elems/thread ----------------------------
__global__ __launch_bounds__(256) void cast_bf16x8(
    const float* __restrict__ in, u16* __restrict__ out)
{
  size_t i = ((size_t)blockIdx.x*256 + threadIdx.x)*8;
  float4 a = *(const float4*)(in + i);
  float4 b = *(const float4*)(in + i + 4);
  uint4 v;
  v.x = (u32)f2bf(a.x) | ((u32)f2bf(a.y) << 16);
  v.y = (u32)f2bf(a.z) | ((u32)f2bf(a.w) << 16);
  v.z = (u32)f2bf(b.x) | ((u32)f2bf(b.y) << 16);
  v.w = (u32)f2bf(b.z) | ((u32)f2bf(b.w) << 16);
  *(uint4*)(out + i) = v;
}

// ---------------- transpose + cast + zero-pad: out[n][k] = in[k][n] -----------
__global__ void transpose_cast(const float* __restrict__ in, u16* __restrict__ out,
                               int R, int Cc, int outR, int outC)
{
  __shared__ float t[32][33];
  const int tx = threadIdx.x, ty = threadIdx.y;
  const int bx = blockIdx.x*32, by = blockIdx.y*32;
  #pragma unroll
  for (int i=0;i<4;++i){
    int r = bx + ty + i*8, c = by + tx;
    t[ty+i*8][tx] = (r<R && c<Cc) ? in[(size_t)r*Cc + c] : 0.f;
  }
  __syncthreads();
  #pragma unroll
  for (int i=0;i<4;++i){
    int orow = by + ty + i*8, ocol = bx + tx;
    if (orow<outR && ocol<outC) out[(size_t)orow*outC + ocol] = f2bf(t[tx][ty+i*8]);
  }
}

// ---------------- bf16 MFMA GEMM: C[M][N] = A[M][K] @ BT[N][K]^T ---------------
// 128x128 tile, BK=32, 4 waves, reg-prefetch + XOR-swizzled LDS (round-3 form).
__global__ __launch_bounds__(256) void gemm_bf16(
    const u16* __restrict__ A, const u16* __restrict__ BT, u16* __restrict__ C,
    int M, int N, int K)
{
  __shared__ __align__(16) u16 As[128*32];
  __shared__ __align__(16) u16 Bs[128*32];
  const int tid = threadIdx.x;
  const int bm = blockIdx.y*128, bn = blockIdx.x*128;
  const int w = tid>>6, lane = tid&63, lg = lane>>4, li = lane&15;
  const int wr = w>>1, wc = w&1;
  const int srow = tid>>2, q = tid&3;
  const int swz = (q ^ (srow&3)) << 3;

  const u16* Ap  = A  + (size_t)(bm+srow)*K + q*8;
  const u16* Ap2 = Ap + (size_t)64*K;
  const u16* Bp  = BT + (size_t)(bn+srow)*K + q*8;
  const u16* Bp2 = Bp + (size_t)64*K;
  u16* aw  = &As[srow*32 + swz];
  u16* aw2 = &As[(srow+64)*32 + swz];
  u16* bw  = &Bs[srow*32 + swz];
  u16* bw2 = &Bs[(srow+64)*32 + swz];
  const int rsw = (lg ^ (li&3)) << 3;
  const u16* ar = &As[(wr*64+li)*32 + rsw];
  const u16* br = &Bs[(wc*64+li)*32 + rsw];

  f32x4 acc[4][4];
  #pragma unroll
  for (int m=0;m<4;++m)
    #pragma unroll
    for (int n=0;n<4;++n) acc[m][n] = (f32x4){0.f,0.f,0.f,0.f};

  const int nk = K >> 5;
  bf16x8 ra  = *(const bf16x8*)Ap;
  bf16x8 ra2 = *(const bf16x8*)Ap2;
  bf16x8 rb  = *(const bf16x8*)Bp;
  bf16x8 rb2 = *(const bf16x8*)Bp2;
  for (int kt=0; kt<nk; ++kt){
    __syncthreads();
    *(bf16x8*)aw = ra;  *(bf16x8*)aw2 = ra2;
    *(bf16x8*)bw = rb;  *(bf16x8*)bw2 = rb2;
    __syncthreads();
    if (kt+1 < nk){
      const int ko = (kt+1)*32;
      ra  = *(const bf16x8*)(Ap+ko);  ra2 = *(const bf16x8*)(Ap2+ko);
      rb  = *(const bf16x8*)(Bp+ko);  rb2 = *(const bf16x8*)(Bp2+ko);
    }
    bf16x8 af[4], bg[4];
    #pragma unroll
    for (int m=0;m<4;++m) af[m] = *(const bf16x8*)(ar + m*16*32);
    #pragma unroll
    for (int n=0;n<4;++n) bg[n] = *(const bf16x8*)(br + n*16*32);
    #pragma unroll
    for (int m=0;m<4;++m)
      #pragma unroll
      for (int n=0;n<4;++n)
        acc[m][n] = __builtin_amdgcn_mfma_f32_16x16x32_bf16(af[m], bg[n], acc[m][n], 0,0,0);
  }
  #pragma unroll
  for (int m=0;m<4;++m){
    const int row = bm + wr*64 + m*16 + lg*4;
    #pragma unroll
    for (int n=0;n<4;++n){
      const int col = bn + wc*64 + n*16 + li;
      #pragma unroll
      for (int r=0;r<4;++r)
        C[(size_t)(row+r)*N + col] = f2bf(acc[m][n][r]);
    }
  }
}

// ---------------- kv_full(bf16) -> rmsnorm+project kv_pt(bf16 pad), rotary k_pe
__global__ __launch_bounds__(256) void build_kvpt(
    const u16* __restrict__ kvfull,  // [S][640], cols 0..575 valid
    const float* __restrict__ gamma,
    const float* __restrict__ fc, const float* __restrict__ fs,
    u16* __restrict__ kvpt,          // [S][544]
    float* __restrict__ kpe)         // [S][64]
{
  const int s = blockIdx.x, tid = threadIdx.x;
  const int wv = tid>>6, lane = tid&63;
  const u16* src = kvfull + (size_t)s*640;
  __shared__ float red1[4], red2[4];
  float v0 = bf2f(src[tid]), v1 = bf2f(src[tid+256]);
  float sq = v0*v0 + v1*v1;
  #pragma unroll
  for (int off=32; off; off>>=1) sq += __shfl_down(sq, off);
  if (lane==0) red1[wv]=sq;
  __syncthreads();
  float tot = red1[0]+red1[1]+red1[2]+red1[3];
  float rinv = 1.0f/sqrtf(tot*(1.0f/512.0f)+1e-6f);
  float n0 = v0*rinv*gamma[tid], n1 = v1*rinv*gamma[tid+256];
  float s2 = n0*n0+n1*n1;
  #pragma unroll
  for (int off=32; off; off>>=1) s2 += __shfl_down(s2, off);
  if (lane==0) red2[wv]=s2;
  __syncthreads();
  u16* dst = kvpt + (size_t)s*544;
  dst[1+tid]   = f2bf(n0);
  dst[257+tid] = f2bf(n1);
  if (tid==0) dst[0] = f2bf(sqrtf(red2[0]+red2[1]+red2[2]+red2[3]+1.0f));
  if (tid<31) dst[513+tid] = 0;
  if (tid<32){
    float x0 = bf2f(src[512+2*tid]), x1 = bf2f(src[513+2*tid]);
    float c = fc[(size_t)s*32+tid], sn = fs[(size_t)s*32+tid];
    kpe[(size_t)s*64 + 2*tid]   = x0*c - x1*sn;
    kpe[(size_t)s*64 + 2*tid+1] = x0*sn + x1*c;
  }
}

// ---------------- q_raw(bf16) -> rotary + Lorentz project (time NEGATED) ------
__global__ __launch_bounds__(64) void build_qproj(
    const u16* __restrict__ qraw,    // [S][3072]
    const float* __restrict__ fc, const float* __restrict__ fs,
    u16* __restrict__ qp)            // [NH][S][224]
{
  const int s = blockIdx.x, h = blockIdx.y, lane = threadIdx.x;
  const u16* src = qraw + (size_t)s*3072 + h*192;
  u16* dst = qp + ((size_t)h*S_LEN + s)*DPAD;
  u16 e0 = src[lane], e1 = src[lane+64];
  float f0 = bf2f(e0), f1 = bf2f(e1);
  dst[1+lane] = e0; dst[65+lane] = e1;
  float sq = f0*f0 + f1*f1;
  if (lane < 32){
    float x0 = bf2f(src[128+2*lane]), x1 = bf2f(src[129+2*lane]);
    float c = fc[(size_t)s*32+lane], sn = fs[(size_t)s*32+lane];
    float y0 = x0*c - x1*sn, y1 = x0*sn + x1*c;
    dst[129+2*lane] = f2bf(y0); dst[130+2*lane] = f2bf(y1);
    sq += y0*y0 + y1*y1;
  }
  if (lane < 31) dst[193+lane] = 0;
  #pragma unroll
  for (int off=32; off; off>>=1) sq += __shfl_down(sq, off);
  if (lane==0) dst[0] = f2bf(-sqrtf(sq+1.0f));   // Minkowski sign folded in
}

// ---------------- kvb(bf16) -> k_proj [NH][S][224], v_projT [NH][128][S] ------
__global__ __launch_bounds__(64) void build_kvproj(
    const u16* __restrict__ kvb,   // [S][4096], head h at cols h*255..+254
    const float* __restrict__ kpe,
    u16* __restrict__ kp,          // [NH][S][224]
    u16* __restrict__ vt)          // [NH][128][S]
{
  const int s = blockIdx.x, h = blockIdx.y, lane = threadIdx.x;
  const u16* src = kvb + (size_t)s*4096 + h*255;
  u16* kdst = kp + ((size_t)h*S_LEN + s)*DPAD;
  u16 a0 = src[lane], a1 = src[lane+64];
  float fa0 = bf2f(a0), fa1 = bf2f(a1);
  float pe = kpe[(size_t)s*64 + lane];
  kdst[1+lane] = a0; kdst[65+lane] = a1; kdst[129+lane] = f2bf(pe);
  if (lane<31) kdst[193+lane] = 0;
  float sq = fa0*fa0 + fa1*fa1 + pe*pe;
  #pragma unroll
  for (int off=32; off; off>>=1) sq += __shfl_down(sq, off);
  if (lane==0) kdst[0] = f2bf(sqrtf(sq+1.0f));
  u16 b0 = src[128+lane];
  u16 b1 = (lane<63) ? src[192+lane] : (u16)0;
  float fb0 = bf2f(b0), fb1 = bf2f(b1);
  u16* vbase = vt + (size_t)h*128*S_LEN;
  vbase[(size_t)(1+lane)*S_LEN + s] = b0;
  if (lane<63) vbase[(size_t)(65+lane)*S_LEN + s] = b1;
  float sv = fb0*fb0 + fb1*fb1;
  #pragma unroll
  for (int off=32; off; off>>=1) sv += __shfl_down(sv, off);
  if (lane==0) vbase[s] = f2bf(sqrtf(sv+1.0f));
}

// ---------------- key-split flash attention: uniform wave units ---------------
// wave unit = (h, strip s16 of 16 q-rows, chunk c of 256 keys), c*16 <= s16.
// 576 units/head; block = 4 consecutive units of one head; grid 144*16=2304.
// slot(h,s16,c) = h*576 + c*128 - c*(c-1)*8 + (s16 - 16*c).
__global__ __launch_bounds__(256) void attn_part(
    const u16* __restrict__ qp,   // [NH][S][224] (time negated)
    const u16* __restrict__ kp,   // [NH][S][224]
    const u16* __restrict__ vt,   // [NH][128][S]
    const float* __restrict__ ss,
    float* __restrict__ Opart,    // [9216 slots][16][128]
    float* __restrict__ ml)       // [9216 slots][16][2]
{
  const int h  = blockIdx.x & 15;
  const int ub = blockIdx.x >> 4;          // 0..143
  const int w = threadIdx.x>>6, lane = threadIdx.x&63;
  const int u = ub*4 + w;                  // 0..575
  int c = 0, rem = u;
  while (rem >= 128 - 16*c){ rem -= 128 - 16*c; ++c; }
  const int s16 = c*16 + rem;              // c*16 <= s16 <= 127
  const int lg = lane>>4, li = lane&15;
  const int r0 = s16*16;
  const float cl2 = (2.0f/ss[0]) * 1.44269504088896f;
  __shared__ __align__(16) u16 P[4][16][72];

  const u16* qb = qp + ((size_t)h*S_LEN + r0 + li)*DPAD + lg*8;
  bf16x8 qf[7];
  #pragma unroll
  for (int d=0; d<7; ++d) qf[d] = *(const bf16x8*)(qb + d*32);

  f32x4 of[8];
  #pragma unroll
  for (int d=0; d<8; ++d) of[d] = (f32x4){0.f,0.f,0.f,0.f};
  float mreg[4] = {-3e38f,-3e38f,-3e38f,-3e38f};
  float lreg[4] = {0.f,0.f,0.f,0.f};

  const int t0 = c*4;
  const int tE = min(c*4+3, (r0+15)>>6);
  for (int t=t0; t<=tE; ++t){
    const int k0 = t*64;
    const u16* kb = kp + ((size_t)h*S_LEN + k0 + li)*DPAD + lg*8;
    f32x4 s[4];
    #pragma unroll
    for (int j=0;j<4;++j) s[j] = (f32x4){0.f,0.f,0.f,0.f};
    #pragma unroll
    for (int d=0; d<7; ++d){
      #pragma unroll
      for (int j=0;j<4;++j){
        bf16x8 kf = *(const bf16x8*)(kb + j*16*DPAD + d*32);
        s[j] = __builtin_amdgcn_mfma_f32_16x16x32_bf16(qf[d], kf, s[j], 0,0,0);
      }
    }
    // prefetch V low half — hides latency under softmax
    const u16* vb = vt + ((size_t)h*128 + li)*S_LEN + k0 + lg*8;
    bf16x8 vlo[8];
    #pragma unroll
    for (int d=0;d<8;++d) vlo[d] = *(const bf16x8*)(vb + (size_t)d*16*S_LEN);

    float alpha[4];
    #pragma unroll
    for (int r=0;r<4;++r){
      const int row = r0 + lg*4 + r;
      float a0 = (k0 + li      <= row) ? s[0][r] : -3e38f;
      float a1 = (k0 + 16 + li <= row) ? s[1][r] : -3e38f;
      float a2 = (k0 + 32 + li <= row) ? s[2][r] : -3e38f;
      float a3 = (k0 + 48 + li <= row) ? s[3][r] : -3e38f;
      float mx = fmaxf(fmaxf(a0,a1), fmaxf(a2,a3));
      mx = fmaxf(mx, __shfl_xor(mx,1));
      mx = fmaxf(mx, __shfl_xor(mx,2));
      mx = fmaxf(mx, __shfl_xor(mx,4));
      mx = fmaxf(mx, __shfl_xor(mx,8));
      float mn = fmaxf(mreg[r], mx);
      alpha[r] = exp2f((mreg[r]-mn)*cl2);
      mreg[r] = mn;
      float e0 = exp2f((a0-mn)*cl2);
      float e1 = exp2f((a1-mn)*cl2);
      float e2 = exp2f((a2-mn)*cl2);
      float e3 = exp2f((a3-mn)*cl2);
      float ls = (e0+e1)+(e2+e3);
      ls += __shfl_xor(ls,1);
      ls += __shfl_xor(ls,2);
      ls += __shfl_xor(ls,4);
      ls += __shfl_xor(ls,8);
      lreg[r] = lreg[r]*alpha[r] + ls;
      P[w][lg*4+r][li]    = f2bf(e0);
      P[w][lg*4+r][li+16] = f2bf(e1);
      P[w][lg*4+r][li+32] = f2bf(e2);
      P[w][lg*4+r][li+48] = f2bf(e3);
    }
    #pragma unroll
    for (int d=0;d<8;++d){
      of[d][0]*=alpha[0]; of[d][1]*=alpha[1];
      of[d][2]*=alpha[2]; of[d][3]*=alpha[3];
    }
    bf16x8 pa0 = *(const bf16x8*)(&P[w][li][lg*8]);
    bf16x8 pa1 = *(const bf16x8*)(&P[w][li][32+lg*8]);
    #pragma unroll
    for (int d=0;d<8;++d){
      bf16x8 vhi = *(const bf16x8*)(vb + (size_t)d*16*S_LEN + 32);
      of[d] = __builtin_amdgcn_mfma_f32_16x16x32_bf16(pa0, vlo[d], of[d], 0,0,0);
      of[d] = __builtin_amdgcn_mfma_f32_16x16x32_bf16(pa1, vhi,    of[d], 0,0,0);
    }
  }
  const int slot = h*576 + c*128 - (c*(c-1))*8 + (s16 - 16*c);
  float* ob = Opart + (size_t)slot*2048;
  #pragma unroll
  for (int r=0;r<4;++r){
    const int rw = lg*4 + r;
    #pragma unroll
    for (int d=0;d<8;++d) ob[(size_t)rw*128 + d*16 + li] = of[d][r];
    if (li == 0){
      ml[((size_t)slot*16 + rw)*2]   = mreg[r];
      ml[((size_t)slot*16 + rw)*2+1] = lreg[r];
    }
  }
}

// ---------------- combine partials + Lorentz centroid epilogue ----------------
// block = (h, s16 strip): 16 rows x 128 cols; up to 8 chunk partials.
__global__ __launch_bounds__(256) void attn_combine(
    const float* __restrict__ Opart, const float* __restrict__ ml,
    const float* __restrict__ ss, u16* __restrict__ out)  // [S][2048] bf16
{
  const int h = blockIdx.x & 15;
  const int s16 = blockIdx.x >> 4;       // 0..127
  const int nc = (s16 >> 4) + 1;         // 1..8 chunks
  const int tid = threadIdx.x;
  const int row = tid >> 4;              // 0..15
  const int ci  = tid & 15;              // cols ci*8 .. ci*8+7
  const float cl2 = (2.0f/ss[0]) * 1.44269504088896f;

  int slot[8];
  #pragma unroll
  for (int c=0;c<8;++c) slot[c] = h*576 + c*128 - (c*(c-1))*8 + (s16 - 16*c);

  float m[8], l[8];
  float mstar = -3e38f;
  #pragma unroll
  for (int c=0;c<8;++c){
    if (c < nc){
      float2 v = *(const float2*)(ml + ((size_t)slot[c]*16 + row)*2);
      m[c] = v.x; l[c] = v.y;
    } else { m[c] = -3e38f; l[c] = 0.f; }
    mstar = fmaxf(mstar, m[c]);
  }
  float lstar = 0.f; float wgt[8];
  #pragma unroll
  for (int c=0;c<8;++c){ wgt[c] = exp2f((m[c]-mstar)*cl2); lstar += l[c]*wgt[c]; }
  float linv = 1.0f/lstar;

  float av[8];
  float o[8] = {0.f,0.f,0.f,0.f,0.f,0.f,0.f,0.f};
  #pragma unroll
  for (int c=0;c<8;++c){
    if (c < nc){
      const float* pb = Opart + (size_t)slot[c]*2048 + row*128 + ci*8;
      float4 p0 = *(const float4*)(pb);
      float4 p1 = *(const float4*)(pb+4);
      o[0] += p0.x*wgt[c]; o[1] += p0.y*wgt[c]; o[2] += p0.z*wgt[c]; o[3] += p0.w*wgt[c];
      o[4] += p1.x*wgt[c]; o[5] += p1.y*wgt[c]; o[6] += p1.z*wgt[c]; o[7] += p1.w*wgt[c];
    }
  }
  float part = 0.f;
  #pragma unroll
  for (int j=0;j<8;++j){ av[j] = o[j]*linv; part += av[j]*av[j]; }
  if (ci==0) part -= 2.f*av[0]*av[0];     // col 0 = time component
  part += __shfl_xor(part,1);
  part += __shfl_xor(part,2);
  part += __shfl_xor(part,4);
  part += __shfl_xor(part,8);
  float sc = 1.0f/sqrtf(fmaxf(fabsf(part),1e-8f));
  u16* ob = out + (size_t)(s16*16+row)*2048 + h*128 + ci*8;
  #pragma unroll
  for (int j=0;j<8;++j) ob[j] = f2bf(av[j]*sc);
}

// ---------------- final projection: out = [sqrt(|y|^2+1), y] (f32 out) --------
__global__ __launch_bounds__(256) void final_project(
    const u16* __restrict__ y,  // [S][2048], cols 0..2046 valid
    float* __restrict__ out)    // [S][2048]
{
  const int s = blockIdx.x, tid = threadIdx.x;
  const int wv = tid>>6, lane = tid&63;
  const u16* src = y + (size_t)s*2048;
  float* dst = out + (size_t)s*2048;
  float sq = 0.f;
  for (int j=tid; j<2047; j+=256){
    float v = bf2f(src[j]);
    dst[1+j] = v;
    sq += v*v;
  }
  __shared__ float red[4];
  #pragma unroll
  for (int off=32; off; off>>=1) sq += __shfl_down(sq, off);
  if (lane==0) red[wv]=sq;
  __syncthreads();
  if (tid==0) dst[0] = sqrtf(red[0]+red[1]+red[2]+red[3]+1.0f);
}

extern "C" void kernel_launch(void* const* d_in, const int* in_sizes, int n_in,
                              void* d_out, int out_size, void* d_ws, size_t ws_size,
                              hipStream_t stream) {
  const float* x    = (const float*)d_in[0];
  const float* fc   = (const float*)d_in[2];
  const float* fs   = (const float*)d_in[3];
  const float* wq   = (const float*)d_in[5];
  const float* wkva = (const float*)d_in[6];
  const float* gam  = (const float*)d_in[7];
  const float* wkvb = (const float*)d_in[8];
  const float* wo   = (const float*)d_in[9];
  const float* ssp  = (const float*)d_in[10];
  float* out = (float*)d_out;
  char* base = (char*)d_ws;

  // Region A (pre-attention, all dead before attn_part):
  u16*   xb     = (u16*)(base + 0);           // [2048][2048] bf16
  u16*   wqT    = (u16*)(base + 8388608);     // [3072][2048]
  u16*   wkvaT  = (u16*)(base + 20971520);    // [640][2048]
  u16*   wkvbT  = (u16*)(base + 23592960);    // [4096][544]
  u16*   kvfull = (u16*)(base + 28049408);    // [2048][640]
  u16*   kvpt   = (u16*)(base + 30670848);    // [2048][544]
  float* kpe    = (float*)(base + 32899072);  // [2048][64]
  u16*   kvb    = (u16*)(base + 33423360);    // [2048][4096]
  // Region B (dead after build_qproj):
  u16*   qraw   = (u16*)(base + 69206016);    // [2048][3072]
  // Region C (attention inputs):
  u16*   qproj  = (u16*)(base + 81788928);    // [16][2048][224]
  u16*   kproj  = (u16*)(base + 96468992);    // [16][2048][224]
  u16*   vprojT = (u16*)(base + 111149056);   // [16][128][2048], end 119.5 MB
  // Attention phase (A+B dead):
  float* Opart  = (float*)(base + 0);         // 9216*16*128*4 = 75,497,472
  float* mlbuf  = (float*)(base + 75497472);  // 9216*16*2*4  =  1,179,648
  u16*   attn_o = (u16*)(base + 76677120);    // [2048][2048] bf16 (overlaps dead qraw/qproj tail region safely post-attn_part)
  // Output phase (Opart dead after combine):
  u16*   woT    = (u16*)(base + 0);           // [2048][2048]
  u16*   yb     = (u16*)(base + 8388608);     // [2048][2048]

  dim3 tb(32,8);
  cast_bf16x8<<<2048, 256, 0, stream>>>(x, xb);
  transpose_cast<<<dim3(64,96),  tb, 0, stream>>>(wq,   wqT,   2048, 3072, 3072, 2048);
  transpose_cast<<<dim3(64,20),  tb, 0, stream>>>(wkva, wkvaT, 2048,  576,  640, 2048);
  gemm_bf16<<<dim3(24,16), 256, 0, stream>>>(xb, wqT,   qraw,   2048, 3072, 2048);
  gemm_bf16<<<dim3(5,16),  256, 0, stream>>>(xb, wkvaT, kvfull, 2048,  640, 2048);
  build_kvpt<<<2048, 256, 0, stream>>>(kvfull, gam, fc, fs, kvpt, kpe);
  transpose_cast<<<dim3(17,128), tb, 0, stream>>>(wkvb, wkvbT,  513, 4080, 4096,  544);
  gemm_bf16<<<dim3(32,16), 256, 0, stream>>>(kvpt, wkvbT, kvb,  2048, 4096,  544);
  build_qproj<<<dim3(2048,16), 64, 0, stream>>>(qraw, fc, fs, qproj);
  build_kvproj<<<dim3(2048,16), 64, 0, stream>>>(kvb, kpe, kproj, vprojT);
  attn_part<<<2304, 256, 0, stream>>>(qproj, kproj, vprojT, ssp, Opart, mlbuf);
  attn_combine<<<2048, 256, 0, stream>>>(Opart, mlbuf, ssp, attn_o);
  transpose_cast<<<dim3(64,64), tb, 0, stream>>>(wo, woT, 2048, 2047, 2048, 2048);
  gemm_bf16<<<dim3(16,16), 256, 0, stream>>>(attn_o, woT, yb, 2048, 2048, 2048);
  final_project<<<2048, 256, 0, stream>>>(yb, out);
}

// Round 7
// 453.330 us; speedup vs baseline: 1.3549x; 1.0680x over previous
//
#include <hip/hip_runtime.h>
#include <math.h>

// LorentzMLA — bf16 MFMA implementation.
// Round 7: fix round-6 LDS swizzle non-bijectivity: K-tile row stride padded
// 448B -> 512B (multiple of 128B) so byte^((row&7)<<4) is closed per row.

typedef unsigned short u16;
typedef unsigned int u32;
typedef __attribute__((ext_vector_type(8))) short bf16x8;
typedef __attribute__((ext_vector_type(4))) float f32x4;

#define S_LEN 2048
#define NH 16
#define DPAD 224

__device__ __forceinline__ u16 f2bf(float f){
  u32 u = __builtin_bit_cast(u32, f);
  u32 r = u + 0x7fffu + ((u >> 16) & 1u);
  return (u16)(r >> 16);
}
__device__ __forceinline__ float bf2f(u16 h){
  u32 u = ((u32)h) << 16;
  return __builtin_bit_cast(float, u);
}

// ---------------- f32 -> bf16 cast, 8 elems/thread ----------------------------
__global__ __launch_bounds__(256) void cast_bf16x8(
    const float* __restrict__ in, u16* __restrict__ out)
{
  size_t i = ((size_t)blockIdx.x*256 + threadIdx.x)*8;
  float4 a = *(const float4*)(in + i);
  float4 b = *(const float4*)(in + i + 4);
  uint4 v;
  v.x = (u32)f2bf(a.x) | ((u32)f2bf(a.y) << 16);
  v.y = (u32)f2bf(a.z) | ((u32)f2bf(a.w) << 16);
  v.z = (u32)f2bf(b.x) | ((u32)f2bf(b.y) << 16);
  v.w = (u32)f2bf(b.z) | ((u32)f2bf(b.w) << 16);
  *(uint4*)(out + i) = v;
}

// ---------------- transpose + cast + zero-pad: out[n][k] = in[k][n] -----------
__global__ void transpose_cast(const float* __restrict__ in, u16* __restrict__ out,
                               int R, int Cc, int outR, int outC)
{
  __shared__ float t[32][33];
  const int tx = threadIdx.x, ty = threadIdx.y;
  const int bx = blockIdx.x*32, by = blockIdx.y*32;
  #pragma unroll
  for (int i=0;i<4;++i){
    int r = bx + ty + i*8, c = by + tx;
    t[ty+i*8][tx] = (r<R && c<Cc) ? in[(size_t)r*Cc + c] : 0.f;
  }
  __syncthreads();
  #pragma unroll
  for (int i=0;i<4;++i){
    int orow = by + ty + i*8, ocol = bx + tx;
    if (orow<outR && ocol<outC) out[(size_t)orow*outC + ocol] = f2bf(t[tx][ty+i*8]);
  }
}

// ---------------- bf16 MFMA GEMM: C[M][N] = A[M][K] @ BT[N][K]^T ---------------
// 128x128 tile, BK=32, 4 waves, reg-prefetch + XOR-swizzled LDS.
__global__ __launch_bounds__(256) void gemm_bf16(
    const u16* __restrict__ A, const u16* __restrict__ BT, u16* __restrict__ C,
    int M, int N, int K)
{
  __shared__ __align__(16) u16 As[128*32];
  __shared__ __align__(16) u16 Bs[128*32];
  const int tid = threadIdx.x;
  const int bm = blockIdx.y*128, bn = blockIdx.x*128;
  const int w = tid>>6, lane = tid&63, lg = lane>>4, li = lane&15;
  const int wr = w>>1, wc = w&1;
  const int srow = tid>>2, q = tid&3;
  const int swz = (q ^ (srow&3)) << 3;

  const u16* Ap  = A  + (size_t)(bm+srow)*K + q*8;
  const u16* Ap2 = Ap + (size_t)64*K;
  const u16* Bp  = BT + (size_t)(bn+srow)*K + q*8;
  const u16* Bp2 = Bp + (size_t)64*K;
  u16* aw  = &As[srow*32 + swz];
  u16* aw2 = &As[(srow+64)*32 + swz];
  u16* bw  = &Bs[srow*32 + swz];
  u16* bw2 = &Bs[(srow+64)*32 + swz];
  const int rsw = (lg ^ (li&3)) << 3;
  const u16* ar = &As[(wr*64+li)*32 + rsw];
  const u16* br = &Bs[(wc*64+li)*32 + rsw];

  f32x4 acc[4][4];
  #pragma unroll
  for (int m=0;m<4;++m)
    #pragma unroll
    for (int n=0;n<4;++n) acc[m][n] = (f32x4){0.f,0.f,0.f,0.f};

  const int nk = K >> 5;
  bf16x8 ra  = *(const bf16x8*)Ap;
  bf16x8 ra2 = *(const bf16x8*)Ap2;
  bf16x8 rb  = *(const bf16x8*)Bp;
  bf16x8 rb2 = *(const bf16x8*)Bp2;
  for (int kt=0; kt<nk; ++kt){
    __syncthreads();
    *(bf16x8*)aw = ra;  *(bf16x8*)aw2 = ra2;
    *(bf16x8*)bw = rb;  *(bf16x8*)bw2 = rb2;
    __syncthreads();
    if (kt+1 < nk){
      const int ko = (kt+1)*32;
      ra  = *(const bf16x8*)(Ap+ko);  ra2 = *(const bf16x8*)(Ap2+ko);
      rb  = *(const bf16x8*)(Bp+ko);  rb2 = *(const bf16x8*)(Bp2+ko);
    }
    bf16x8 af[4], bg[4];
    #pragma unroll
    for (int m=0;m<4;++m) af[m] = *(const bf16x8*)(ar + m*16*32);
    #pragma unroll
    for (int n=0;n<4;++n) bg[n] = *(const bf16x8*)(br + n*16*32);
    #pragma unroll
    for (int m=0;m<4;++m)
      #pragma unroll
      for (int n=0;n<4;++n)
        acc[m][n] = __builtin_amdgcn_mfma_f32_16x16x32_bf16(af[m], bg[n], acc[m][n], 0,0,0);
  }
  #pragma unroll
  for (int m=0;m<4;++m){
    const int row = bm + wr*64 + m*16 + lg*4;
    #pragma unroll
    for (int n=0;n<4;++n){
      const int col = bn + wc*64 + n*16 + li;
      #pragma unroll
      for (int r=0;r<4;++r)
        C[(size_t)(row+r)*N + col] = f2bf(acc[m][n][r]);
    }
  }
}

// ---------------- kv_full(bf16) -> rmsnorm+project kv_pt(bf16 pad), rotary k_pe
__global__ __launch_bounds__(256) void build_kvpt(
    const u16* __restrict__ kvfull,  // [S][640], cols 0..575 valid
    const float* __restrict__ gamma,
    const float* __restrict__ fc, const float* __restrict__ fs,
    u16* __restrict__ kvpt,          // [S][544]
    float* __restrict__ kpe)         // [S][64]
{
  const int s = blockIdx.x, tid = threadIdx.x;
  const int wv = tid>>6, lane = tid&63;
  const u16* src = kvfull + (size_t)s*640;
  __shared__ float red1[4], red2[4];
  float v0 = bf2f(src[tid]), v1 = bf2f(src[tid+256]);
  float sq = v0*v0 + v1*v1;
  #pragma unroll
  for (int off=32; off; off>>=1) sq += __shfl_down(sq, off);
  if (lane==0) red1[wv]=sq;
  __syncthreads();
  float tot = red1[0]+red1[1]+red1[2]+red1[3];
  float rinv = 1.0f/sqrtf(tot*(1.0f/512.0f)+1e-6f);
  float n0 = v0*rinv*gamma[tid], n1 = v1*rinv*gamma[tid+256];
  float s2 = n0*n0+n1*n1;
  #pragma unroll
  for (int off=32; off; off>>=1) s2 += __shfl_down(s2, off);
  if (lane==0) red2[wv]=s2;
  __syncthreads();
  u16* dst = kvpt + (size_t)s*544;
  dst[1+tid]   = f2bf(n0);
  dst[257+tid] = f2bf(n1);
  if (tid==0) dst[0] = f2bf(sqrtf(red2[0]+red2[1]+red2[2]+red2[3]+1.0f));
  if (tid<31) dst[513+tid] = 0;
  if (tid<32){
    float x0 = bf2f(src[512+2*tid]), x1 = bf2f(src[513+2*tid]);
    float c = fc[(size_t)s*32+tid], sn = fs[(size_t)s*32+tid];
    kpe[(size_t)s*64 + 2*tid]   = x0*c - x1*sn;
    kpe[(size_t)s*64 + 2*tid+1] = x0*sn + x1*c;
  }
}

// ---------------- q_raw(bf16) -> rotary + Lorentz project (time NEGATED) ------
__global__ __launch_bounds__(64) void build_qproj(
    const u16* __restrict__ qraw,    // [S][3072]
    const float* __restrict__ fc, const float* __restrict__ fs,
    u16* __restrict__ qp)            // [NH][S][224]
{
  const int s = blockIdx.x, h = blockIdx.y, lane = threadIdx.x;
  const u16* src = qraw + (size_t)s*3072 + h*192;
  u16* dst = qp + ((size_t)h*S_LEN + s)*DPAD;
  u16 e0 = src[lane], e1 = src[lane+64];
  float f0 = bf2f(e0), f1 = bf2f(e1);
  dst[1+lane] = e0; dst[65+lane] = e1;
  float sq = f0*f0 + f1*f1;
  if (lane < 32){
    float x0 = bf2f(src[128+2*lane]), x1 = bf2f(src[129+2*lane]);
    float c = fc[(size_t)s*32+lane], sn = fs[(size_t)s*32+lane];
    float y0 = x0*c - x1*sn, y1 = x0*sn + x1*c;
    dst[129+2*lane] = f2bf(y0); dst[130+2*lane] = f2bf(y1);
    sq += y0*y0 + y1*y1;
  }
  if (lane < 31) dst[193+lane] = 0;
  #pragma unroll
  for (int off=32; off; off>>=1) sq += __shfl_down(sq, off);
  if (lane==0) dst[0] = f2bf(-sqrtf(sq+1.0f));   // Minkowski sign folded in
}

// ---------------- kvb(bf16) -> k_proj [NH][S][224], v_projT [NH][128][S] ------
__global__ __launch_bounds__(64) void build_kvproj(
    const u16* __restrict__ kvb,   // [S][4096], head h at cols h*255..+254
    const float* __restrict__ kpe,
    u16* __restrict__ kp,          // [NH][S][224]
    u16* __restrict__ vt)          // [NH][128][S]
{
  const int s = blockIdx.x, h = blockIdx.y, lane = threadIdx.x;
  const u16* src = kvb + (size_t)s*4096 + h*255;
  u16* kdst = kp + ((size_t)h*S_LEN + s)*DPAD;
  u16 a0 = src[lane], a1 = src[lane+64];
  float fa0 = bf2f(a0), fa1 = bf2f(a1);
  float pe = kpe[(size_t)s*64 + lane];
  kdst[1+lane] = a0; kdst[65+lane] = a1; kdst[129+lane] = f2bf(pe);
  if (lane<31) kdst[193+lane] = 0;
  float sq = fa0*fa0 + fa1*fa1 + pe*pe;
  #pragma unroll
  for (int off=32; off; off>>=1) sq += __shfl_down(sq, off);
  if (lane==0) kdst[0] = f2bf(sqrtf(sq+1.0f));
  u16 b0 = src[128+lane];
  u16 b1 = (lane<63) ? src[192+lane] : (u16)0;
  float fb0 = bf2f(b0), fb1 = bf2f(b1);
  u16* vbase = vt + (size_t)h*128*S_LEN;
  vbase[(size_t)(1+lane)*S_LEN + s] = b0;
  if (lane<63) vbase[(size_t)(65+lane)*S_LEN + s] = b1;
  float sv = fb0*fb0 + fb1*fb1;
  #pragma unroll
  for (int off=32; off; off>>=1) sv += __shfl_down(sv, off);
  if (lane==0) vbase[s] = f2bf(sqrtf(sv+1.0f));
}

// ---------------- key-split flash attention, block-cooperative K in LDS -------
// block = (h, strip of 64 q-rows, chunk c of 256 keys), c <= strip/4.
// K-tile 64 rows x 224 cols staged in LDS with 512B row stride (pad 64B) and
// byte ^= ((row&7)<<4) swizzle — bijective per row since 512 % 128 == 0.
__global__ __launch_bounds__(256) void attn_part(
    const u16* __restrict__ qp,   // [NH][S][224] (time negated)
    const u16* __restrict__ kp,   // [NH][S][224]
    const u16* __restrict__ vt,   // [NH][128][S]
    const float* __restrict__ ss,
    float* __restrict__ Opart,    // [9216 slots][16][128]
    float* __restrict__ ml)       // [9216 slots][16][2]
{
  const int h  = blockIdx.x & 15;
  int ub = blockIdx.x >> 4;                // 0..143
  int c = 0;
  while (ub >= 32 - 4*c){ ub -= 32 - 4*c; ++c; }
  const int strip = 4*c + ub;              // 0..31, strip >= 4c
  const int tid = threadIdx.x;
  const int w = tid>>6, lane = tid&63;
  const int lg = lane>>4, li = lane&15;
  const int r0 = strip*64 + w*16;
  const float cl2 = (2.0f/ss[0]) * 1.44269504088896f;
  __shared__ __align__(16) u16 Ks[64*256];         // 512B-stride swizzled K tile
  __shared__ __align__(16) u16 P[4][16][72];

  // staging geometry: 1792 16B-chunks (28/row), 7 per thread
  u16* dstp[7]; int rowv[7], ocv[7];
  #pragma unroll
  for (int i=0;i<7;++i){
    int p = tid + i*256;
    int r = p/28, oc = p - r*28;
    rowv[i] = r; ocv[i] = oc;
    dstp[i] = Ks + ((r*512 + ((oc*16) ^ ((r&7)<<4))) >> 1);
  }

  const u16* qb = qp + ((size_t)h*S_LEN + r0 + li)*DPAD + lg*8;
  bf16x8 qf[7];
  #pragma unroll
  for (int d=0; d<7; ++d) qf[d] = *(const bf16x8*)(qb + d*32);

  f32x4 of[8];
  #pragma unroll
  for (int d=0; d<8; ++d) of[d] = (f32x4){0.f,0.f,0.f,0.f};
  float mreg[4] = {-3e38f,-3e38f,-3e38f,-3e38f};
  float lreg[4] = {0.f,0.f,0.f,0.f};

  const int t0 = c*4;
  const int tE = min(c*4+3, strip);        // wave-independent trip count
  const u16* khead = kp + (size_t)h*S_LEN*DPAD;

  bf16x8 kst[7];
  {
    const u16* kb0 = khead + (size_t)(t0*64)*DPAD;
    #pragma unroll
    for (int i=0;i<7;++i) kst[i] = *(const bf16x8*)(kb0 + (size_t)rowv[i]*DPAD + ocv[i]*8);
  }

  for (int t=t0; t<=tE; ++t){
    const int k0 = t*64;
    __syncthreads();                       // all waves done reading prev tile
    #pragma unroll
    for (int i=0;i<7;++i) *(bf16x8*)dstp[i] = kst[i];
    if (t < tE){                           // prefetch next tile (stays in flight)
      const u16* kbn = khead + (size_t)((t+1)*64)*DPAD;
      #pragma unroll
      for (int i=0;i<7;++i) kst[i] = *(const bf16x8*)(kbn + (size_t)rowv[i]*DPAD + ocv[i]*8);
    }
    asm volatile("s_waitcnt lgkmcnt(0)" ::: "memory");
    __builtin_amdgcn_s_barrier();          // raw: vmcnt prefetch NOT drained

    // QK^T from swizzled LDS: row = li + j*16, (row&7) == (li&7)
    f32x4 s[4];
    #pragma unroll
    for (int j=0;j<4;++j) s[j] = (f32x4){0.f,0.f,0.f,0.f};
    const int xs = (li&7)<<4;
    __builtin_amdgcn_s_setprio(1);
    #pragma unroll
    for (int d=0; d<7; ++d){
      #pragma unroll
      for (int j=0;j<4;++j){
        const bf16x8 kf = *(const bf16x8*)(Ks + (((li + j*16)*512 + ((lg*16 + d*64) ^ xs)) >> 1));
        s[j] = __builtin_amdgcn_mfma_f32_16x16x32_bf16(qf[d], kf, s[j], 0,0,0);
      }
    }
    __builtin_amdgcn_s_setprio(0);

    float alpha[4];
    #pragma unroll
    for (int r=0;r<4;++r){
      const int row = r0 + lg*4 + r;
      float a0 = (k0 + li      <= row) ? s[0][r] : -3e38f;
      float a1 = (k0 + 16 + li <= row) ? s[1][r] : -3e38f;
      float a2 = (k0 + 32 + li <= row) ? s[2][r] : -3e38f;
      float a3 = (k0 + 48 + li <= row) ? s[3][r] : -3e38f;
      float mx = fmaxf(fmaxf(a0,a1), fmaxf(a2,a3));
      mx = fmaxf(mx, __shfl_xor(mx,1));
      mx = fmaxf(mx, __shfl_xor(mx,2));
      mx = fmaxf(mx, __shfl_xor(mx,4));
      mx = fmaxf(mx, __shfl_xor(mx,8));
      float mn = fmaxf(mreg[r], mx);
      alpha[r] = exp2f((mreg[r]-mn)*cl2);
      mreg[r] = mn;
      float e0 = exp2f((a0-mn)*cl2);
      float e1 = exp2f((a1-mn)*cl2);
      float e2 = exp2f((a2-mn)*cl2);
      float e3 = exp2f((a3-mn)*cl2);
      float ls = (e0+e1)+(e2+e3);
      ls += __shfl_xor(ls,1);
      ls += __shfl_xor(ls,2);
      ls += __shfl_xor(ls,4);
      ls += __shfl_xor(ls,8);
      lreg[r] = lreg[r]*alpha[r] + ls;
      P[w][lg*4+r][li]    = f2bf(e0);
      P[w][lg*4+r][li+16] = f2bf(e1);
      P[w][lg*4+r][li+32] = f2bf(e2);
      P[w][lg*4+r][li+48] = f2bf(e3);
    }
    #pragma unroll
    for (int d=0;d<8;++d){
      of[d][0]*=alpha[0]; of[d][1]*=alpha[1];
      of[d][2]*=alpha[2]; of[d][3]*=alpha[3];
    }
    bf16x8 pa0 = *(const bf16x8*)(&P[w][li][lg*8]);      // same-wave LDS, no barrier
    bf16x8 pa1 = *(const bf16x8*)(&P[w][li][32+lg*8]);
    const u16* vb = vt + ((size_t)h*128 + li)*S_LEN + k0 + lg*8;
    __builtin_amdgcn_s_setprio(1);
    #pragma unroll
    for (int d=0;d<8;++d){
      bf16x8 vf0 = *(const bf16x8*)(vb + (size_t)d*16*S_LEN);
      bf16x8 vf1 = *(const bf16x8*)(vb + (size_t)d*16*S_LEN + 32);
      of[d] = __builtin_amdgcn_mfma_f32_16x16x32_bf16(pa0, vf0, of[d], 0,0,0);
      of[d] = __builtin_amdgcn_mfma_f32_16x16x32_bf16(pa1, vf1, of[d], 0,0,0);
    }
    __builtin_amdgcn_s_setprio(0);
  }

  // slot = (h*144 + off(c) + (strip-4c))*4 + w, off(c) = 32c - 2c(c-1)
  const int slot = (h*144 + 32*c - 2*c*(c-1) + (strip - 4*c))*4 + w;
  float* ob = Opart + (size_t)slot*2048;
  #pragma unroll
  for (int r=0;r<4;++r){
    const int rw = lg*4 + r;
    #pragma unroll
    for (int d=0;d<8;++d) ob[(size_t)rw*128 + d*16 + li] = of[d][r];
    if (li == 0){
      ml[((size_t)slot*16 + rw)*2]   = mreg[r];
      ml[((size_t)slot*16 + rw)*2+1] = lreg[r];
    }
  }
}

// ---------------- combine partials + Lorentz centroid epilogue ----------------
// block = (h, s16 strip of 16 rows); strip64 = s16>>2, w = s16&3.
__global__ __launch_bounds__(256) void attn_combine(
    const float* __restrict__ Opart, const float* __restrict__ ml,
    const float* __restrict__ ss, u16* __restrict__ out)  // [S][2048] bf16
{
  const int h = blockIdx.x & 15;
  const int s16 = blockIdx.x >> 4;       // 0..127
  const int strip = s16 >> 2, wv = s16 & 3;
  const int nc = (s16 >> 4) + 1;         // chunks c = 0..strip/4
  const int tid = threadIdx.x;
  const int row = tid >> 4;              // 0..15
  const int ci  = tid & 15;              // cols ci*8 .. ci*8+7
  const float cl2 = (2.0f/ss[0]) * 1.44269504088896f;

  int slot[8];
  #pragma unroll
  for (int c=0;c<8;++c)
    slot[c] = (h*144 + 32*c - 2*c*(c-1) + (strip - 4*c))*4 + wv;

  float m[8], l[8];
  float mstar = -3e38f;
  #pragma unroll
  for (int c=0;c<8;++c){
    if (c < nc){
      float2 v = *(const float2*)(ml + ((size_t)slot[c]*16 + row)*2);
      m[c] = v.x; l[c] = v.y;
    } else { m[c] = -3e38f; l[c] = 0.f; }
    mstar = fmaxf(mstar, m[c]);
  }
  float lstar = 0.f; float wgt[8];
  #pragma unroll
  for (int c=0;c<8;++c){ wgt[c] = exp2f((m[c]-mstar)*cl2); lstar += l[c]*wgt[c]; }
  float linv = 1.0f/lstar;

  float av[8];
  float o[8] = {0.f,0.f,0.f,0.f,0.f,0.f,0.f,0.f};
  #pragma unroll
  for (int c=0;c<8;++c){
    if (c < nc){
      const float* pb = Opart + (size_t)slot[c]*2048 + row*128 + ci*8;
      float4 p0 = *(const float4*)(pb);
      float4 p1 = *(const float4*)(pb+4);
      o[0] += p0.x*wgt[c]; o[1] += p0.y*wgt[c]; o[2] += p0.z*wgt[c]; o[3] += p0.w*wgt[c];
      o[4] += p1.x*wgt[c]; o[5] += p1.y*wgt[c]; o[6] += p1.z*wgt[c]; o[7] += p1.w*wgt[c];
    }
  }
  float part = 0.f;
  #pragma unroll
  for (int j=0;j<8;++j){ av[j] = o[j]*linv; part += av[j]*av[j]; }
  if (ci==0) part -= 2.f*av[0]*av[0];     // col 0 = time component
  part += __shfl_xor(part,1);
  part += __shfl_xor(part,2);
  part += __shfl_xor(part,4);
  part += __shfl_xor(part,8);
  float sc = 1.0f/sqrtf(fmaxf(fabsf(part),1e-8f));
  u16* ob = out + (size_t)(s16*16+row)*2048 + h*128 + ci*8;
  #pragma unroll
  for (int j=0;j<8;++j) ob[j] = f2bf(av[j]*sc);
}

// ---------------- final projection: out = [sqrt(|y|^2+1), y] (f32 out) --------
__global__ __launch_bounds__(256) void final_project(
    const u16* __restrict__ y,  // [S][2048], cols 0..2046 valid
    float* __restrict__ out)    // [S][2048]
{
  const int s = blockIdx.x, tid = threadIdx.x;
  const int wv = tid>>6, lane = tid&63;
  const u16* src = y + (size_t)s*2048;
  float* dst = out + (size_t)s*2048;
  float sq = 0.f;
  for (int j=tid; j<2047; j+=256){
    float v = bf2f(src[j]);
    dst[1+j] = v;
    sq += v*v;
  }
  __shared__ float red[4];
  #pragma unroll
  for (int off=32; off; off>>=1) sq += __shfl_down(sq, off);
  if (lane==0) red[wv]=sq;
  __syncthreads();
  if (tid==0) dst[0] = sqrtf(red[0]+red[1]+red[2]+red[3]+1.0f);
}

extern "C" void kernel_launch(void* const* d_in, const int* in_sizes, int n_in,
                              void* d_out, int out_size, void* d_ws, size_t ws_size,
                              hipStream_t stream) {
  const float* x    = (const float*)d_in[0];
  const float* fc   = (const float*)d_in[2];
  const float* fs   = (const float*)d_in[3];
  const float* wq   = (const float*)d_in[5];
  const float* wkva = (const float*)d_in[6];
  const float* gam  = (const float*)d_in[7];
  const float* wkvb = (const float*)d_in[8];
  const float* wo   = (const float*)d_in[9];
  const float* ssp  = (const float*)d_in[10];
  float* out = (float*)d_out;
  char* base = (char*)d_ws;

  // Region A (pre-attention, all dead before attn_part):
  u16*   xb     = (u16*)(base + 0);           // [2048][2048] bf16
  u16*   wqT    = (u16*)(base + 8388608);     // [3072][2048]
  u16*   wkvaT  = (u16*)(base + 20971520);    // [640][2048]
  u16*   wkvbT  = (u16*)(base + 23592960);    // [4096][544]
  u16*   kvfull = (u16*)(base + 28049408);    // [2048][640]
  u16*   kvpt   = (u16*)(base + 30670848);    // [2048][544]
  float* kpe    = (float*)(base + 32899072);  // [2048][64]
  u16*   kvb    = (u16*)(base + 33423360);    // [2048][4096]
  // Region B (dead after build_qproj):
  u16*   qraw   = (u16*)(base + 69206016);    // [2048][3072]
  // Region C (attention inputs):
  u16*   qproj  = (u16*)(base + 81788928);    // [16][2048][224]
  u16*   kproj  = (u16*)(base + 96468992);    // [16][2048][224]
  u16*   vprojT = (u16*)(base + 111149056);   // [16][128][2048], end 119.5 MB
  // Attention phase (A+B dead):
  float* Opart  = (float*)(base + 0);         // 9216*16*128*4 = 75,497,472
  float* mlbuf  = (float*)(base + 75497472);  // 9216*16*2*4  =  1,179,648
  u16*   attn_o = (u16*)(base + 76677120);    // [2048][2048] bf16
  // Output phase (Opart dead after combine):
  u16*   woT    = (u16*)(base + 0);           // [2048][2048]
  u16*   yb     = (u16*)(base + 8388608);     // [2048][2048]

  dim3 tb(32,8);
  cast_bf16x8<<<2048, 256, 0, stream>>>(x, xb);
  transpose_cast<<<dim3(64,96),  tb, 0, stream>>>(wq,   wqT,   2048, 3072, 3072, 2048);
  transpose_cast<<<dim3(64,20),  tb, 0, stream>>>(wkva, wkvaT, 2048,  576,  640, 2048);
  gemm_bf16<<<dim3(24,16), 256, 0, stream>>>(xb, wqT,   qraw,   2048, 3072, 2048);
  gemm_bf16<<<dim3(5,16),  256, 0, stream>>>(xb, wkvaT, kvfull, 2048,  640, 2048);
  build_kvpt<<<2048, 256, 0, stream>>>(kvfull, gam, fc, fs, kvpt, kpe);
  transpose_cast<<<dim3(17,128), tb, 0, stream>>>(wkvb, wkvbT,  513, 4080, 4096,  544);
  gemm_bf16<<<dim3(32,16), 256, 0, stream>>>(kvpt, wkvbT, kvb,  2048, 4096,  544);
  build_qproj<<<dim3(2048,16), 64, 0, stream>>>(qraw, fc, fs, qproj);
  build_kvproj<<<dim3(2048,16), 64, 0, stream>>>(kvb, kpe, kproj, vprojT);
  attn_part<<<2304, 256, 0, stream>>>(qproj, kproj, vprojT, ssp, Opart, mlbuf);
  attn_combine<<<2048, 256, 0, stream>>>(Opart, mlbuf, ssp, attn_o);
  transpose_cast<<<dim3(64,64), tb, 0, stream>>>(wo, woT, 2048, 2047, 2048, 2048);
  gemm_bf16<<<dim3(16,16), 256, 0, stream>>>(attn_o, woT, yb, 2048, 2048, 2048);
  final_project<<<2048, 256, 0, stream>>>(yb, out);
}